// Round 2
// baseline (1294.595 us; speedup 1.0000x reference)
//
#include <hip/hip_runtime.h>
#include <hip/hip_bf16.h>

#define DI static __device__ __forceinline__

namespace {

constexpr int H = 160, W = 160, HW = H * W;

// ---- workspace layout (float offsets) ----
constexpr size_t WBUF = 0;                      // transposed weights + biases (131072 floats)
constexpr size_t BUF1 = 131072;                 // 16*32*HW = 13,107,200 floats
constexpr size_t BUF2 = BUF1 + 13107200;        // 13,107,200 floats
constexpr size_t MEAN_NCHW = BUF2 + 13107200;   // 4*32*HW = 3,276,800
constexpr size_t MEAN_NHWC = MEAN_NCHW + 3276800;
// total ws need = MEAN_NHWC + 3,276,800 = 32,899,072 floats = ~125.5 MiB

// ---- offsets inside WBUF ----
constexpr int W1T = 0,      B1T = 2400;    // 3*25*32
constexpr int W2T = 2432,   B2T = 28032;   // 32*25*32
constexpr int W3T = 28064,  B3T = 37280;   // 32*9*32
constexpr int WOT = 37312,  BOT = 77312;   // 32*25*50
constexpr int WDT = 77376,  BDT = 102976;  // 32*25*32
constexpr int W4T = 103008, B4T = 112224;  // 32*9*32
constexpr int W5T = 112256, B5T = 113120;  // 32*9*3

constexpr int N_PREP = 2400+32 + 25600+32 + 9216+32 + 40000+50 + 25600+32 + 9216+32 + 864+3;

} // namespace

// ---------------- prep: transpose weights to [ic][tap][oc], fold BN ----------------
DI void transpose_w(int i, const float* __restrict__ w, const float* g, const float* v,
                    int IC, int KK, int OC, float* __restrict__ dst) {
    int ic = i / (KK * OC);
    int r  = i % (KK * OC);
    int t  = r / OC;
    int oc = r % OC;
    float s = g ? g[oc] * rsqrtf(v[oc] + 1e-5f) : 1.f;
    dst[i] = w[(oc * IC + ic) * KK + t] * s;
}

DI void make_bias(int i, const float* __restrict__ b, const float* g, const float* be,
                  const float* m, const float* v, float* __restrict__ dst) {
    if (g) {
        float s = g[i] * rsqrtf(v[i] + 1e-5f);
        dst[i] = s * (b[i] - m[i]) + be[i];
    } else {
        dst[i] = b[i];
    }
}

__global__ void prep_k(
    const float* __restrict__ w1, const float* __restrict__ b1, const float* __restrict__ g1,
    const float* __restrict__ be1, const float* __restrict__ m1, const float* __restrict__ v1,
    const float* __restrict__ w2, const float* __restrict__ b2, const float* __restrict__ g2,
    const float* __restrict__ be2, const float* __restrict__ m2, const float* __restrict__ v2,
    const float* __restrict__ w3, const float* __restrict__ b3,
    const float* __restrict__ wo, const float* __restrict__ bo,
    const float* __restrict__ wd, const float* __restrict__ bd,
    const float* __restrict__ w4, const float* __restrict__ b4, const float* __restrict__ g4,
    const float* __restrict__ be4, const float* __restrict__ m4, const float* __restrict__ v4,
    const float* __restrict__ w5, const float* __restrict__ b5,
    float* __restrict__ wb)
{
    int j = blockIdx.x * 256 + threadIdx.x;
    if (j >= N_PREP) return;
    if (j < 2400)  { transpose_w(j, w1, g1, v1, 3, 25, 32, wb + W1T); return; } j -= 2400;
    if (j < 32)    { make_bias(j, b1, g1, be1, m1, v1, wb + B1T); return; }     j -= 32;
    if (j < 25600) { transpose_w(j, w2, g2, v2, 32, 25, 32, wb + W2T); return; } j -= 25600;
    if (j < 32)    { make_bias(j, b2, g2, be2, m2, v2, wb + B2T); return; }     j -= 32;
    if (j < 9216)  { transpose_w(j, w3, nullptr, nullptr, 32, 9, 32, wb + W3T); return; } j -= 9216;
    if (j < 32)    { make_bias(j, b3, nullptr, nullptr, nullptr, nullptr, wb + B3T); return; } j -= 32;
    if (j < 40000) { transpose_w(j, wo, nullptr, nullptr, 32, 25, 50, wb + WOT); return; } j -= 40000;
    if (j < 50)    { make_bias(j, bo, nullptr, nullptr, nullptr, nullptr, wb + BOT); return; } j -= 50;
    if (j < 25600) { transpose_w(j, wd, nullptr, nullptr, 32, 25, 32, wb + WDT); return; } j -= 25600;
    if (j < 32)    { make_bias(j, bd, nullptr, nullptr, nullptr, nullptr, wb + BDT); return; } j -= 32;
    if (j < 9216)  { transpose_w(j, w4, g4, v4, 32, 9, 32, wb + W4T); return; } j -= 9216;
    if (j < 32)    { make_bias(j, b4, g4, be4, m4, v4, wb + B4T); return; }     j -= 32;
    if (j < 864)   { transpose_w(j, w5, nullptr, nullptr, 32, 9, 3, wb + W5T); return; } j -= 864;
    if (j < 3)     { make_bias(j, b5, nullptr, nullptr, nullptr, nullptr, wb + B5T); return; }
}

// ---------------- generic tiled direct conv ----------------
// wT layout: [IC][KS*KS][OC], bias [OC]. grid = B*100 blocks, 256 threads.
template<int IC, int OC, int KS, int PAD, bool RELU, bool NHWC_OUT>
__global__ __launch_bounds__(256) void conv_k(
    const float* __restrict__ in, const float* __restrict__ wT,
    const float* __restrict__ bias, float* __restrict__ out)
{
    constexpr int T = 16, TP = T + KS - 1, KK = KS * KS;
    __shared__ float tile[IC * TP * TP];

    const int bx = blockIdx.x % 10, by = (blockIdx.x / 10) % 10, b = blockIdx.x / 100;
    const int tx = threadIdx.x & 15, ty = threadIdx.x >> 4;
    const int x0 = bx * T, y0 = by * T;

    const float* inb = in + (size_t)b * IC * HW;
    for (int i = threadIdx.x; i < IC * TP * TP; i += 256) {
        int ic = i / (TP * TP), r = i % (TP * TP), yy = r / TP, xx = r % TP;
        int gy = y0 + yy - PAD, gx = x0 + xx - PAD;
        tile[i] = (gy >= 0 && gy < H && gx >= 0 && gx < W) ? inb[ic * HW + gy * W + gx] : 0.f;
    }
    __syncthreads();

    float acc[OC];
#pragma unroll
    for (int o = 0; o < OC; ++o) acc[o] = 0.f;

    for (int ic = 0; ic < IC; ++ic) {
        const float* tp = tile + ic * TP * TP + ty * TP + tx;
        const float* wp = wT + (size_t)ic * KK * OC;
#pragma unroll
        for (int t = 0; t < KK; ++t) {
            float v = tp[(t / KS) * TP + (t % KS)];
#pragma unroll
            for (int o = 0; o < OC; ++o)
                acc[o] = fmaf(v, wp[t * OC + o], acc[o]);
        }
    }

    const int gy = y0 + ty, gx = x0 + tx;
    if (NHWC_OUT) {
        float* ob = out + (((size_t)b * H + gy) * W + gx) * OC;
#pragma unroll
        for (int o = 0; o < OC; ++o) {
            float r = acc[o] + bias[o];
            if (RELU) r = fmaxf(r, 0.f);
            ob[o] = r;
        }
    } else {
        float* ob = out + (size_t)b * OC * HW + gy * W + gx;
#pragma unroll
        for (int o = 0; o < OC; ++o) {
            float r = acc[o] + bias[o];
            if (RELU) r = fmaxf(r, 0.f);
            ob[(size_t)o * HW] = r;
        }
    }
}

// ---------------- conv3 (3x3) fused with mean over N=4; dual-layout output ----------------
__global__ __launch_bounds__(256) void conv3_mean_k(
    const float* __restrict__ in,   // [16,32,H,W]
    const float* __restrict__ wT, const float* __restrict__ bias,
    float* __restrict__ outNCHW,    // [4,32,H,W]
    float* __restrict__ outNHWC)    // [4,H,W,32]
{
    constexpr int IC = 32, OC = 32, KS = 3, PAD = 1, T = 16, TP = 18, KK = 9;
    __shared__ float tile[IC * TP * TP];

    const int bx = blockIdx.x % 10, by = (blockIdx.x / 10) % 10, b = blockIdx.x / 100;
    const int tx = threadIdx.x & 15, ty = threadIdx.x >> 4;
    const int x0 = bx * T, y0 = by * T;

    float acc[OC];
#pragma unroll
    for (int o = 0; o < OC; ++o) acc[o] = 0.f;

    for (int n = 0; n < 4; ++n) {
        if (n) __syncthreads();
        const float* inb = in + (size_t)(b * 4 + n) * IC * HW;
        for (int i = threadIdx.x; i < IC * TP * TP; i += 256) {
            int ic = i / (TP * TP), r = i % (TP * TP), yy = r / TP, xx = r % TP;
            int gy = y0 + yy - PAD, gx = x0 + xx - PAD;
            tile[i] = (gy >= 0 && gy < H && gx >= 0 && gx < W) ? inb[ic * HW + gy * W + gx] : 0.f;
        }
        __syncthreads();

        for (int ic = 0; ic < IC; ++ic) {
            const float* tp = tile + ic * TP * TP + ty * TP + tx;
            const float* wp = wT + (size_t)ic * KK * OC;
#pragma unroll
            for (int t = 0; t < KK; ++t) {
                float v = tp[(t / KS) * TP + (t % KS)];
#pragma unroll
                for (int o = 0; o < OC; ++o)
                    acc[o] = fmaf(v, wp[t * OC + o], acc[o]);
            }
        }
    }

    const int gy = y0 + ty, gx = x0 + tx;
    float* o1 = outNCHW + (size_t)b * OC * HW + gy * W + gx;
    float* o2 = outNHWC + (((size_t)b * H + gy) * W + gx) * OC;
#pragma unroll
    for (int o = 0; o < OC; ++o) {
        float r = acc[o] * 0.25f + bias[o];
        o1[(size_t)o * HW] = r;
        o2[o] = r;
    }
}

// ---------------- deformable conv (bilinear gather + 5x5x32->32) ----------------
__global__ __launch_bounds__(256) void deform_k(
    const float* __restrict__ xn,   // NHWC [4,H,W,32]
    const float* __restrict__ offs, // NHWC [4,H,W,50]
    const float* __restrict__ wT,   // [ic][25][oc]
    const float* __restrict__ bias,
    float* __restrict__ out)        // NCHW [4,32,H,W]
{
    const int idx = blockIdx.x * 256 + threadIdx.x;   // grid covers 4*HW exactly
    const int x = idx % W;
    const int t1 = idx / W;
    const int y = t1 % H;
    const int b = t1 / H;

    float acc[32];
#pragma unroll
    for (int o = 0; o < 32; ++o) acc[o] = 0.f;

    const float* op = offs + (size_t)idx * 50;
    const float* xb = xn + (size_t)b * HW * 32;

    for (int t = 0; t < 25; ++t) {
        const int ky = t / 5, kx = t % 5;
        float dy = op[2 * t], dx = op[2 * t + 1];
        float py = (float)(y - 2 + ky) + dy;
        float px = (float)(x - 2 + kx) + dx;
        float fy = floorf(py), fx = floorf(px);
        float wy = py - fy, wx = px - fx;
        int iy = (int)fy, ix = (int)fx;

        float v[32];
#pragma unroll
        for (int q = 0; q < 32; ++q) v[q] = 0.f;

#pragma unroll
        for (int c = 0; c < 4; ++c) {
            int yy = iy + (c >> 1), xx = ix + (c & 1);
            float wc = ((c >> 1) ? wy : 1.f - wy) * ((c & 1) ? wx : 1.f - wx);
            if (yy >= 0 && yy < H && xx >= 0 && xx < W) {
                const float* g = xb + ((size_t)yy * W + xx) * 32;
#pragma unroll
                for (int q = 0; q < 8; ++q) {
                    float4 gg = *(const float4*)(g + q * 4);
                    v[q * 4 + 0] = fmaf(wc, gg.x, v[q * 4 + 0]);
                    v[q * 4 + 1] = fmaf(wc, gg.y, v[q * 4 + 1]);
                    v[q * 4 + 2] = fmaf(wc, gg.z, v[q * 4 + 2]);
                    v[q * 4 + 3] = fmaf(wc, gg.w, v[q * 4 + 3]);
                }
            }
        }

#pragma unroll
        for (int ic = 0; ic < 32; ++ic) {
            float vv = v[ic];
            const float* wpp = wT + ((size_t)ic * 25 + t) * 32;
#pragma unroll
            for (int o = 0; o < 32; ++o)
                acc[o] = fmaf(vv, wpp[o], acc[o]);
        }
    }

    float* ob = out + (size_t)b * 32 * HW + y * W + x;
#pragma unroll
    for (int o = 0; o < 32; ++o) ob[(size_t)o * HW] = acc[o] + bias[o];
}

// ---------------- final conv (3x3, 32->3) + tanh + fp32 store ----------------
__global__ __launch_bounds__(256) void conv5_tanh_k(
    const float* __restrict__ in, const float* __restrict__ wT,
    const float* __restrict__ bias, float* __restrict__ out)
{
    constexpr int IC = 32, OC = 3, KS = 3, PAD = 1, T = 16, TP = 18, KK = 9;
    __shared__ float tile[IC * TP * TP];

    const int bx = blockIdx.x % 10, by = (blockIdx.x / 10) % 10, b = blockIdx.x / 100;
    const int tx = threadIdx.x & 15, ty = threadIdx.x >> 4;
    const int x0 = bx * T, y0 = by * T;

    const float* inb = in + (size_t)b * IC * HW;
    for (int i = threadIdx.x; i < IC * TP * TP; i += 256) {
        int ic = i / (TP * TP), r = i % (TP * TP), yy = r / TP, xx = r % TP;
        int gy = y0 + yy - PAD, gx = x0 + xx - PAD;
        tile[i] = (gy >= 0 && gy < H && gx >= 0 && gx < W) ? inb[ic * HW + gy * W + gx] : 0.f;
    }
    __syncthreads();

    float acc[OC];
#pragma unroll
    for (int o = 0; o < OC; ++o) acc[o] = 0.f;

    for (int ic = 0; ic < IC; ++ic) {
        const float* tp = tile + ic * TP * TP + ty * TP + tx;
        const float* wp = wT + (size_t)ic * KK * OC;
#pragma unroll
        for (int t = 0; t < KK; ++t) {
            float v = tp[(t / KS) * TP + (t % KS)];
#pragma unroll
            for (int o = 0; o < OC; ++o)
                acc[o] = fmaf(v, wp[t * OC + o], acc[o]);
        }
    }

    const int gy = y0 + ty, gx = x0 + tx;
    float* ob = out + (size_t)b * OC * HW + gy * W + gx;
#pragma unroll
    for (int o = 0; o < OC; ++o) {
        float r = tanhf(acc[o] + bias[o]);
        ob[(size_t)o * HW] = r;
    }
}

// ---------------- launch ----------------
extern "C" void kernel_launch(void* const* d_in, const int* in_sizes, int n_in,
                              void* d_out, int out_size, void* d_ws, size_t ws_size,
                              hipStream_t stream)
{
    const float* rg  = (const float*)d_in[0];
    const float* w1  = (const float*)d_in[1];  const float* b1 = (const float*)d_in[2];
    const float* g1  = (const float*)d_in[3];  const float* be1 = (const float*)d_in[4];
    const float* m1  = (const float*)d_in[5];  const float* v1 = (const float*)d_in[6];
    const float* w2  = (const float*)d_in[7];  const float* b2 = (const float*)d_in[8];
    const float* g2  = (const float*)d_in[9];  const float* be2 = (const float*)d_in[10];
    const float* m2  = (const float*)d_in[11]; const float* v2 = (const float*)d_in[12];
    const float* w3  = (const float*)d_in[13]; const float* b3 = (const float*)d_in[14];
    const float* wo  = (const float*)d_in[15]; const float* bo = (const float*)d_in[16];
    const float* wd  = (const float*)d_in[17]; const float* bd = (const float*)d_in[18];
    const float* w4  = (const float*)d_in[19]; const float* b4 = (const float*)d_in[20];
    const float* g4  = (const float*)d_in[21]; const float* be4 = (const float*)d_in[22];
    const float* m4  = (const float*)d_in[23]; const float* v4 = (const float*)d_in[24];
    const float* w5  = (const float*)d_in[25]; const float* b5 = (const float*)d_in[26];

    float* ws   = (float*)d_ws;
    float* wb   = ws + WBUF;
    float* buf1 = ws + BUF1;
    float* buf2 = ws + BUF2;
    float* mN   = ws + MEAN_NCHW;
    float* mH   = ws + MEAN_NHWC;
    float* offsb = buf1;                 // conv1 out dead by then
    float* dout  = buf2;                 // conv2 out dead by then
    float* c4    = buf1 + 5120000;       // offsets dead by then (disjoint anyway)
    float* out = (float*)d_out;

    prep_k<<<(N_PREP + 255) / 256, 256, 0, stream>>>(
        w1, b1, g1, be1, m1, v1, w2, b2, g2, be2, m2, v2, w3, b3,
        wo, bo, wd, bd, w4, b4, g4, be4, m4, v4, w5, b5, wb);

    // stage A: 16 images
    conv_k<3, 32, 5, 2, true, false><<<1600, 256, 0, stream>>>(rg,   wb + W1T, wb + B1T, buf1);
    conv_k<32, 32, 5, 2, true, false><<<1600, 256, 0, stream>>>(buf1, wb + W2T, wb + B2T, buf2);
    conv3_mean_k<<<400, 256, 0, stream>>>(buf2, wb + W3T, wb + B3T, mN, mH);

    // stage B: 4 images
    conv_k<32, 50, 5, 2, false, true><<<400, 256, 0, stream>>>(mN, wb + WOT, wb + BOT, offsb);
    deform_k<<<400, 256, 0, stream>>>(mH, offsb, wb + WDT, wb + BDT, dout);
    conv_k<32, 32, 3, 1, true, false><<<400, 256, 0, stream>>>(dout, wb + W4T, wb + B4T, c4);
    conv5_tanh_k<<<400, 256, 0, stream>>>(c4, wb + W5T, wb + B5T, out);
}

// Round 3
// 371.341 us; speedup vs baseline: 3.4863x; 3.4863x over previous
//
#include <hip/hip_runtime.h>
#include <hip/hip_bf16.h>

#define DI static __device__ __forceinline__

typedef __attribute__((ext_vector_type(8)))  short short8v;   // 8 bf16 = 4 VGPR (MFMA A/B frag)
typedef __attribute__((ext_vector_type(4)))  short short4v;   // 8B
typedef __attribute__((ext_vector_type(16))) float f32x16;    // MFMA C/D frag

namespace {
constexpr int H = 160, W = 160, HW = H * W;

// ---- bf16 fragment region (short offsets, base = d_ws + 0) ----
constexpr int Q1 = 0;        // conv1: 25 ksteps * 64 * 8 = 12800
constexpr int Q2 = 12800;    // conv2: 50 * 512 = 25600
constexpr int Q3 = 38400;    // conv3: 18 * 512 = 9216
constexpr int QO = 47616;    // offs : 50 * 2 * 512 = 51200
constexpr int Q4 = 98816;    // conv4: 18 * 512
constexpr int Q5 = 108032;   // conv5: 18 * 512
constexpr int QEND = 117248;

// ---- fp32 region (byte offset, float offsets within) ----
constexpr size_t FPB = 234496;            // = QEND*2
constexpr int WDF = 0;                    // deform weights [ic][25][oc] 25600 f
constexpr int BIAS = 25600;
constexpr int B1 = BIAS, B2 = BIAS + 32, B3 = BIAS + 64, BO = BIAS + 96,
              BD = BIAS + 160, B4 = BIAS + 192, B5 = BIAS + 224;
constexpr int NFP = 25856;

// ---- activation region (byte offset, short offsets within) ----
constexpr size_t ACTB = 337920;           // FPB + NFP*4 = 234496 + 103424
constexpr size_t A1 = 0;                  // conv1 out: 16*HW*32 bf16
constexpr size_t A2 = 13107200;           // conv2 out
constexpr size_t AM = 26214400;           // mean: 4*HW*32
constexpr size_t AO = 29491200;           // offsets: 4*HW*64 (padded 50->64)
constexpr size_t AD = 36044800;           // deform out: 4*HW*32
constexpr size_t A4 = 39321600;           // conv4 out
// end = 42598400 shorts -> total ws use ~85.5 MB

constexpr int NPREP = QEND + 25600 + 256; // 143104 = 559*256 exactly
} // namespace

DI float b2f(short s) {
    unsigned int u = ((unsigned int)(unsigned short)s) << 16;
    float f; __builtin_memcpy(&f, &u, 4); return f;
}
DI short f2b(float f) {
    __hip_bfloat16 h = __float2bfloat16(f);
    short s; __builtin_memcpy(&s, &h, 2); return s;
}

// ---------------- prep: build per-lane MFMA B-fragments + BN fold + biases ----------------
// frag layout: [s][nt][lane][8] bf16, s = (ky*KS+kx)*ICS + h.
// B element: col oc = nt*32 + (lane&31); k = (lane>>5)*8 + j; ic = h*16 + k.
DI void fragw(int j, const float* __restrict__ w, const float* g, const float* v,
              int IC, int KS, int ICS, int NT, int OC, short* __restrict__ dst) {
    int q = j & 7;
    int l = (j >> 3) & 63;
    int rest = j >> 9;            // s*NT + nt
    int nt = rest % NT, s = rest / NT;
    int h = s % ICS, tap = s / ICS;
    int oc = nt * 32 + (l & 31);
    int ic = h * 16 + (l >> 5) * 8 + q;
    float val = 0.f;
    if (oc < OC && ic < IC) {
        val = w[((size_t)(oc * IC + ic)) * (KS * KS) + tap];
        if (g) val *= g[oc] * rsqrtf(v[oc] + 1e-5f);
    }
    dst[j] = f2b(val);
}

__global__ void prep_k(
    const float* __restrict__ w1, const float* __restrict__ b1, const float* __restrict__ g1,
    const float* __restrict__ be1, const float* __restrict__ m1, const float* __restrict__ v1,
    const float* __restrict__ w2, const float* __restrict__ b2, const float* __restrict__ g2,
    const float* __restrict__ be2, const float* __restrict__ m2, const float* __restrict__ v2,
    const float* __restrict__ w3, const float* __restrict__ b3,
    const float* __restrict__ wo, const float* __restrict__ bo,
    const float* __restrict__ wd, const float* __restrict__ bd,
    const float* __restrict__ w4, const float* __restrict__ b4, const float* __restrict__ g4,
    const float* __restrict__ be4, const float* __restrict__ m4, const float* __restrict__ v4,
    const float* __restrict__ w5, const float* __restrict__ b5,
    short* __restrict__ q, float* __restrict__ fp)
{
    int j = blockIdx.x * 256 + threadIdx.x;
    if (j >= NPREP) return;
    if (j < Q2)   { fragw(j - Q1, w1, g1, v1, 3, 5, 1, 1, 32, q + Q1); return; }
    if (j < Q3)   { fragw(j - Q2, w2, g2, v2, 32, 5, 2, 1, 32, q + Q2); return; }
    if (j < QO)   { fragw(j - Q3, w3, nullptr, nullptr, 32, 3, 2, 1, 32, q + Q3); return; }
    if (j < Q4)   { fragw(j - QO, wo, nullptr, nullptr, 32, 5, 2, 2, 50, q + QO); return; }
    if (j < Q5)   { fragw(j - Q4, w4, g4, v4, 32, 3, 2, 1, 32, q + Q4); return; }
    if (j < QEND) { fragw(j - Q5, w5, nullptr, nullptr, 32, 3, 2, 1, 3, q + Q5); return; }
    j -= QEND;
    if (j < 25600) {  // deform weights -> [ic][tap][oc] fp32
        int ic = j / 800, r = j % 800, t = r / 32, o = r % 32;
        fp[WDF + j] = wd[((size_t)o * 32 + ic) * 25 + t];
        return;
    }
    j -= 25600;
    if (j < 32) { float s = g1[j] * rsqrtf(v1[j] + 1e-5f); fp[B1 + j] = s * (b1[j] - m1[j]) + be1[j]; return; } j -= 32;
    if (j < 32) { float s = g2[j] * rsqrtf(v2[j] + 1e-5f); fp[B2 + j] = s * (b2[j] - m2[j]) + be2[j]; return; } j -= 32;
    if (j < 32) { fp[B3 + j] = b3[j]; return; } j -= 32;
    if (j < 64) { fp[BO + j] = (j < 50) ? bo[j] : 0.f; return; } j -= 64;
    if (j < 32) { fp[BD + j] = bd[j]; return; } j -= 32;
    if (j < 32) { float s = g4[j] * rsqrtf(v4[j] + 1e-5f); fp[B4 + j] = s * (b4[j] - m4[j]) + be4[j]; return; } j -= 32;
    if (j < 32) { fp[B5 + j] = (j < 3) ? b5[j] : 0.f; return; }
}

// ---------------- MFMA implicit-GEMM conv ----------------
// Block = 4 waves; wave w computes output row y = yt*4+w, 32 x-positions, 32*NT oc.
// M = 32 x-positions (A row = lane&31), K-step = 16 (half the ic of one tap), N = 32 oc.
// A from LDS (NHWC tile, 72B pixel stride -> conflict-free ds_read_b64 pairs);
// B from global precomputed frags (16B/lane, coalesced, L1-resident).
// OMODE: 0 = bf16 NHWC stride 32; 1 = bf16 NHWC stride 64 (offsets); 2 = tanh fp32 NCHW oc<3.
template<int KS, int ICS, int NT, int NACC, int OMODE, bool RELU, bool IN3>
__global__ __launch_bounds__(256) void mconv_k(
    const void* __restrict__ inv, const short* __restrict__ wq,
    const float* __restrict__ bias, void* __restrict__ outv)
{
    constexpr int PAD = KS / 2, RR = 3 + KS, XX = 31 + KS;
    constexpr int PB = IN3 ? 40 : 72;      // pixel stride bytes (bank-spread, 8B-aligned)
    constexpr int NS = KS * KS * ICS;      // K-steps per image
    __shared__ __align__(16) char lds[RR * XX * PB];

    const int tid = threadIdx.x, w = tid >> 6, l = tid & 63, lx = l & 31, lh = l >> 5;
    const int b = blockIdx.x;
    const int xt = b % 5, yt = (b / 5) % 40, og = b / 200;
    const int gx0 = xt * 32 - PAD, gy0 = yt * 4 - PAD;

    f32x16 acc[NT];
#pragma unroll
    for (int nt = 0; nt < NT; ++nt)
#pragma unroll
        for (int i = 0; i < 16; ++i) acc[nt][i] = 0.f;

    for (int n = 0; n < NACC; ++n) {
        if (n) __syncthreads();
        const int img = og * NACC + n;
        if (IN3) {
            // fp32 NCHW 3-ch input -> bf16, ic padded to 16
            const float* inb = (const float*)inv + (size_t)img * 3 * HW;
            for (int p = tid; p < RR * XX; p += 256) {
                int yy = p / XX, xx = p % XX, gy = gy0 + yy, gx = gx0 + xx;
                bool ok = (gy >= 0) & (gy < H) & (gx >= 0) & (gx < W);
                size_t o = (size_t)gy * W + gx;
                short4v v; v[0] = ok ? f2b(inb[o]) : (short)0;
                v[1] = ok ? f2b(inb[HW + o]) : (short)0;
                v[2] = ok ? f2b(inb[2 * HW + o]) : (short)0; v[3] = 0;
                short4v z; z[0] = z[1] = z[2] = z[3] = 0;
                char* dst = lds + p * PB;
                *(short4v*)dst = v;
                *(short4v*)(dst + 8) = z;
                *(short4v*)(dst + 16) = z;
                *(short4v*)(dst + 24) = z;
            }
        } else {
            // bf16 NHWC 32-ch input, staged in 8B chunks (72B stride is 8B-aligned)
            const short* inb = (const short*)inv + (size_t)img * HW * 32;
            for (int c = tid; c < RR * XX * 8; c += 256) {
                int p = c >> 3, cc = c & 7;
                int yy = p / XX, xx = p % XX, gy = gy0 + yy, gx = gx0 + xx;
                short4v v;
                if ((gy >= 0) & (gy < H) & (gx >= 0) & (gx < W))
                    v = *(const short4v*)(inb + ((size_t)gy * W + gx) * 32 + cc * 4);
                else { v[0] = v[1] = v[2] = v[3] = 0; }
                *(short4v*)(lds + p * PB + cc * 8) = v;
            }
        }
        __syncthreads();

#pragma unroll
        for (int s = 0; s < NS; ++s) {
            const int tap = s / ICS, hh = s % ICS;
            const int ky = tap / KS, kx = tap % KS;
            const char* ap = lds + ((w + ky) * XX + lx + kx) * PB + hh * 32 + lh * 16;
            union { short4v h[2]; short8v v; } u;
            u.h[0] = *(const short4v*)ap;
            u.h[1] = *(const short4v*)(ap + 8);
#pragma unroll
            for (int nt = 0; nt < NT; ++nt) {
                short8v bf = *(const short8v*)(wq + ((size_t)(s * NT + nt) * 64 + l) * 8);
                acc[nt] = __builtin_amdgcn_mfma_f32_32x32x16_bf16(u.v, bf, acc[nt], 0, 0, 0);
            }
        }
    }

    constexpr float MS = (NACC == 4) ? 0.25f : 1.f;
    const int y = yt * 4 + w;
    if (OMODE == 0) {
        const float bb = bias[lx];
        short* ob = (short*)outv + ((size_t)og * HW + (size_t)y * W + xt * 32) * 32 + lx;
#pragma unroll
        for (int r = 0; r < 16; ++r) {
            int row = (r & 3) + 8 * (r >> 2) + 4 * lh;   // x offset within tile
            float vv = acc[0][r] * MS + bb;
            if (RELU) vv = fmaxf(vv, 0.f);
            ob[(size_t)row * 32] = f2b(vv);
        }
    } else if (OMODE == 1) {
        short* ob = (short*)outv + ((size_t)og * HW + (size_t)y * W + xt * 32) * 64;
#pragma unroll
        for (int nt = 0; nt < NT; ++nt) {
            const int oc = nt * 32 + lx;
            const float bb = bias[oc];
#pragma unroll
            for (int r = 0; r < 16; ++r) {
                int row = (r & 3) + 8 * (r >> 2) + 4 * lh;
                ob[(size_t)row * 64 + oc] = f2b(acc[nt][r] + bb);
            }
        }
    } else {
        const int oc = lx;
        const float bb = bias[oc];
        float* ob = (float*)outv;
#pragma unroll
        for (int r = 0; r < 16; ++r) {
            int row = (r & 3) + 8 * (r >> 2) + 4 * lh;
            float vv = tanhf(acc[0][r] + bb);
            if (oc < 3)
                ob[(((size_t)og * 3 + oc) * H + y) * W + xt * 32 + row] = vv;
        }
    }
}

// ---------------- deformable conv (bilinear gather + 5x5x32->32, fp32 VALU) ----------------
__global__ __launch_bounds__(256) void deform_k(
    const short* __restrict__ xn,   // mean, NHWC bf16 [4][HW][32]
    const short* __restrict__ offs, // NHWC bf16 [4][HW][64] (50 used)
    const float* __restrict__ wt,   // [ic][25][oc] fp32
    const float* __restrict__ bias,
    short* __restrict__ out)        // NHWC bf16 [4][HW][32]
{
    const int idx = blockIdx.x * 256 + threadIdx.x;  // 400*256 = 4*HW exactly
    const int x = idx % W;
    const int t1 = idx / W;
    const int y = t1 % H;
    const int b = t1 / H;

    float acc[32];
#pragma unroll
    for (int o = 0; o < 32; ++o) acc[o] = 0.f;

    const short* op = offs + (size_t)idx * 64;
    const short* xb = xn + (size_t)b * HW * 32;

    for (int t = 0; t < 25; ++t) {
        const int ky = t / 5, kx = t % 5;
        float dy = b2f(op[2 * t]), dx = b2f(op[2 * t + 1]);
        float py = (float)(y - 2 + ky) + dy;
        float px = (float)(x - 2 + kx) + dx;
        float fy = floorf(py), fx = floorf(px);
        float wy = py - fy, wx = px - fx;
        int iy = (int)fy, ix = (int)fx;

        float v[32];
#pragma unroll
        for (int q = 0; q < 32; ++q) v[q] = 0.f;

#pragma unroll
        for (int c = 0; c < 4; ++c) {
            int yy = iy + (c >> 1), xx = ix + (c & 1);
            float wc = ((c >> 1) ? wy : 1.f - wy) * ((c & 1) ? wx : 1.f - wx);
            if (yy >= 0 && yy < H && xx >= 0 && xx < W) {
                const short* g = xb + ((size_t)yy * W + xx) * 32;
#pragma unroll
                for (int q8 = 0; q8 < 4; ++q8) {
                    short8v gg = *(const short8v*)(g + q8 * 8);
#pragma unroll
                    for (int j = 0; j < 8; ++j)
                        v[q8 * 8 + j] = fmaf(wc, b2f(gg[j]), v[q8 * 8 + j]);
                }
            }
        }

#pragma unroll
        for (int ic = 0; ic < 32; ++ic) {
            float vv = v[ic];
            const float* wp = wt + ((size_t)ic * 25 + t) * 32;
#pragma unroll
            for (int o = 0; o < 32; ++o)
                acc[o] = fmaf(vv, wp[o], acc[o]);
        }
    }

    short* ob = out + (size_t)idx * 32;
#pragma unroll
    for (int o = 0; o < 32; ++o) ob[o] = f2b(acc[o] + bias[o]);
}

// ---------------- launch ----------------
extern "C" void kernel_launch(void* const* d_in, const int* in_sizes, int n_in,
                              void* d_out, int out_size, void* d_ws, size_t ws_size,
                              hipStream_t stream)
{
    const float* rg  = (const float*)d_in[0];
    const float* w1  = (const float*)d_in[1];  const float* b1 = (const float*)d_in[2];
    const float* g1  = (const float*)d_in[3];  const float* be1 = (const float*)d_in[4];
    const float* m1  = (const float*)d_in[5];  const float* v1 = (const float*)d_in[6];
    const float* w2  = (const float*)d_in[7];  const float* b2 = (const float*)d_in[8];
    const float* g2  = (const float*)d_in[9];  const float* be2 = (const float*)d_in[10];
    const float* m2  = (const float*)d_in[11]; const float* v2 = (const float*)d_in[12];
    const float* w3  = (const float*)d_in[13]; const float* b3 = (const float*)d_in[14];
    const float* wo  = (const float*)d_in[15]; const float* bo = (const float*)d_in[16];
    const float* wd  = (const float*)d_in[17]; const float* bd = (const float*)d_in[18];
    const float* w4  = (const float*)d_in[19]; const float* b4 = (const float*)d_in[20];
    const float* g4  = (const float*)d_in[21]; const float* be4 = (const float*)d_in[22];
    const float* m4  = (const float*)d_in[23]; const float* v4 = (const float*)d_in[24];
    const float* w5  = (const float*)d_in[25]; const float* b5 = (const float*)d_in[26];

    short* q   = (short*)d_ws;
    float* fp  = (float*)((char*)d_ws + FPB);
    short* act = (short*)((char*)d_ws + ACTB);
    short* act1  = act + A1;
    short* act2  = act + A2;
    short* amean = act + AM;
    short* aoffs = act + AO;
    short* adf   = act + AD;
    short* a4o   = act + A4;

    prep_k<<<NPREP / 256, 256, 0, stream>>>(
        w1, b1, g1, be1, m1, v1, w2, b2, g2, be2, m2, v2, w3, b3,
        wo, bo, wd, bd, w4, b4, g4, be4, m4, v4, w5, b5, q, fp);

    // stage A (16 images)
    mconv_k<5, 1, 1, 1, 0, true,  true ><<<3200, 256, 0, stream>>>(rg,   q + Q1, fp + B1, act1);
    mconv_k<5, 2, 1, 1, 0, true,  false><<<3200, 256, 0, stream>>>(act1, q + Q2, fp + B2, act2);
    mconv_k<3, 2, 1, 4, 0, false, false><<< 800, 256, 0, stream>>>(act2, q + Q3, fp + B3, amean);

    // stage B (4 images)
    mconv_k<5, 2, 2, 1, 1, false, false><<< 800, 256, 0, stream>>>(amean, q + QO, fp + BO, aoffs);
    deform_k<<<400, 256, 0, stream>>>(amean, aoffs, fp + WDF, fp + BD, adf);
    mconv_k<3, 2, 1, 1, 0, true,  false><<< 800, 256, 0, stream>>>(adf,  q + Q4, fp + B4, a4o);
    mconv_k<3, 2, 1, 1, 2, false, false><<< 800, 256, 0, stream>>>(a4o,  q + Q5, fp + B5, d_out);
}

// Round 7
// 300.861 us; speedup vs baseline: 4.3030x; 1.2343x over previous
//
#include <hip/hip_runtime.h>
#include <hip/hip_bf16.h>

#define DI static __device__ __forceinline__

typedef __attribute__((ext_vector_type(8)))  short short8v;   // 8 bf16 = 4 VGPR (MFMA A/B frag)
typedef __attribute__((ext_vector_type(4)))  short short4v;   // 8B
typedef __attribute__((ext_vector_type(16))) float f32x16;    // MFMA C/D frag

namespace {
constexpr int H = 160, W = 160, HW = H * W;

// ---- bf16 fragment region (short offsets, base = d_ws + 0) ----
constexpr int Q1 = 0;        // conv1: 25 ksteps * 64 * 8 = 12800
constexpr int Q2 = 12800;    // conv2: 50 * 512 = 25600
constexpr int Q3 = 38400;    // conv3: 18 * 512 = 9216
constexpr int QO = 47616;    // offs : 50 * 2 * 512 = 51200
constexpr int Q4 = 98816;    // conv4: 18 * 512
constexpr int Q5 = 108032;   // conv5: 18 * 512
constexpr int QD = 117248;   // deform: 50 * 512 = 25600
constexpr int QEND = 142848;

// ---- fp32 region (byte offset, float offsets within) ----
constexpr size_t FPB = 285696;            // = QEND*2
constexpr int B1 = 0, B2 = 32, B3 = 64, BO = 96, BD = 160, B4 = 192, B5 = 224;
constexpr int NFP = 256;

// ---- activation region (byte offset, short offsets within) ----
constexpr size_t ACTB = 286720;           // FPB + NFP*4
constexpr size_t A1 = 0;                  // conv1 out: 16*HW*32 bf16
constexpr size_t A2 = 13107200;           // conv2 out
constexpr size_t AM = 26214400;           // mean: 4*HW*32
constexpr size_t AO = 29491200;           // offsets: 4*HW*64 (padded 50->64)
constexpr size_t AD = 36044800;           // deform out: 4*HW*32
constexpr size_t A4 = 39321600;           // conv4 out

constexpr int NPREP = QEND + 256;         // 143104 = 559*256 exactly
} // namespace

DI float b2f(short s) {
    unsigned int u = ((unsigned int)(unsigned short)s) << 16;
    float f; __builtin_memcpy(&f, &u, 4); return f;
}
DI short f2b(float f) {
    __hip_bfloat16 h = __float2bfloat16(f);
    short s; __builtin_memcpy(&s, &h, 2); return s;
}

// ---------------- prep: build per-lane MFMA B-fragments + BN fold + biases ----------------
// frag layout: [s][nt][lane][8] bf16, s = (ky*KS+kx)*ICS + h.
// B element: col oc = nt*32 + (lane&31); k = (lane>>5)*8 + j; ic = h*16 + k.
DI void fragw(int j, const float* __restrict__ w, const float* g, const float* v,
              int IC, int KS, int ICS, int NT, int OC, short* __restrict__ dst) {
    int q = j & 7;
    int l = (j >> 3) & 63;
    int rest = j >> 9;            // s*NT + nt
    int nt = rest % NT, s = rest / NT;
    int h = s % ICS, tap = s / ICS;
    int oc = nt * 32 + (l & 31);
    int ic = h * 16 + (l >> 5) * 8 + q;
    float val = 0.f;
    if (oc < OC && ic < IC) {
        val = w[((size_t)(oc * IC + ic)) * (KS * KS) + tap];
        if (g) val *= g[oc] * rsqrtf(v[oc] + 1e-5f);
    }
    dst[j] = f2b(val);
}

__global__ void prep_k(
    const float* __restrict__ w1, const float* __restrict__ b1, const float* __restrict__ g1,
    const float* __restrict__ be1, const float* __restrict__ m1, const float* __restrict__ v1,
    const float* __restrict__ w2, const float* __restrict__ b2, const float* __restrict__ g2,
    const float* __restrict__ be2, const float* __restrict__ m2, const float* __restrict__ v2,
    const float* __restrict__ w3, const float* __restrict__ b3,
    const float* __restrict__ wo, const float* __restrict__ bo,
    const float* __restrict__ wd, const float* __restrict__ bd,
    const float* __restrict__ w4, const float* __restrict__ b4, const float* __restrict__ g4,
    const float* __restrict__ be4, const float* __restrict__ m4, const float* __restrict__ v4,
    const float* __restrict__ w5, const float* __restrict__ b5,
    short* __restrict__ q, float* __restrict__ fp)
{
    int j = blockIdx.x * 256 + threadIdx.x;
    if (j >= NPREP) return;
    if (j < Q2)   { fragw(j - Q1, w1, g1, v1, 3, 5, 1, 1, 32, q + Q1); return; }
    if (j < Q3)   { fragw(j - Q2, w2, g2, v2, 32, 5, 2, 1, 32, q + Q2); return; }
    if (j < QO)   { fragw(j - Q3, w3, nullptr, nullptr, 32, 3, 2, 1, 32, q + Q3); return; }
    if (j < Q4)   { fragw(j - QO, wo, nullptr, nullptr, 32, 5, 2, 2, 50, q + QO); return; }
    if (j < Q5)   { fragw(j - Q4, w4, g4, v4, 32, 3, 2, 1, 32, q + Q4); return; }
    if (j < QD)   { fragw(j - Q5, w5, nullptr, nullptr, 32, 3, 2, 1, 3, q + Q5); return; }
    if (j < QEND) { fragw(j - QD, wd, nullptr, nullptr, 32, 5, 2, 1, 32, q + QD); return; }
    j -= QEND;
    if (j < 32) { float s = g1[j] * rsqrtf(v1[j] + 1e-5f); fp[B1 + j] = s * (b1[j] - m1[j]) + be1[j]; return; } j -= 32;
    if (j < 32) { float s = g2[j] * rsqrtf(v2[j] + 1e-5f); fp[B2 + j] = s * (b2[j] - m2[j]) + be2[j]; return; } j -= 32;
    if (j < 32) { fp[B3 + j] = b3[j]; return; } j -= 32;
    if (j < 64) { fp[BO + j] = (j < 50) ? bo[j] : 0.f; return; } j -= 64;
    if (j < 32) { fp[BD + j] = bd[j]; return; } j -= 32;
    if (j < 32) { float s = g4[j] * rsqrtf(v4[j] + 1e-5f); fp[B4 + j] = s * (b4[j] - m4[j]) + be4[j]; return; } j -= 32;
    if (j < 32) { fp[B5 + j] = (j < 3) ? b5[j] : 0.f; return; }
}

// ---------------- MFMA implicit-GEMM conv ----------------
// Block = 4 waves; wave w computes output row y = yt*4+w, 32 x-positions, 32*NT oc.
// A from LDS (NHWC tile, 72B pixel stride -> conflict-free ds_read_b64 pairs);
// B from global precomputed frags (16B/lane, coalesced, L1-resident).
// OMODE: 0 = bf16 NHWC stride 32; 1 = bf16 NHWC stride 64 (offsets); 2 = tanh fp32 NCHW oc<3.
template<int KS, int ICS, int NT, int NACC, int OMODE, bool RELU, bool IN3>
__global__ __launch_bounds__(256) void mconv_k(
    const void* __restrict__ inv, const short* __restrict__ wq,
    const float* __restrict__ bias, void* __restrict__ outv)
{
    constexpr int PAD = KS / 2, RR = 3 + KS, XX = 31 + KS;
    constexpr int PB = IN3 ? 40 : 72;      // pixel stride bytes (bank-spread, 8B-aligned)
    constexpr int NS = KS * KS * ICS;      // K-steps per image
    __shared__ __align__(16) char lds[RR * XX * PB];

    const int tid = threadIdx.x, w = tid >> 6, l = tid & 63, lx = l & 31, lh = l >> 5;
    const int b = blockIdx.x;
    const int xt = b % 5, yt = (b / 5) % 40, og = b / 200;
    const int gx0 = xt * 32 - PAD, gy0 = yt * 4 - PAD;

    f32x16 acc[NT];
#pragma unroll
    for (int nt = 0; nt < NT; ++nt)
#pragma unroll
        for (int i = 0; i < 16; ++i) acc[nt][i] = 0.f;

    for (int n = 0; n < NACC; ++n) {
        if (n) __syncthreads();
        const int img = og * NACC + n;
        if (IN3) {
            // fp32 NCHW 3-ch input -> bf16, ic padded to 16
            const float* inb = (const float*)inv + (size_t)img * 3 * HW;
            for (int p = tid; p < RR * XX; p += 256) {
                int yy = p / XX, xx = p % XX, gy = gy0 + yy, gx = gx0 + xx;
                bool ok = (gy >= 0) & (gy < H) & (gx >= 0) & (gx < W);
                size_t o = (size_t)gy * W + gx;
                short4v v; v[0] = ok ? f2b(inb[o]) : (short)0;
                v[1] = ok ? f2b(inb[HW + o]) : (short)0;
                v[2] = ok ? f2b(inb[2 * HW + o]) : (short)0; v[3] = 0;
                short4v z; z[0] = z[1] = z[2] = z[3] = 0;
                char* dst = lds + p * PB;
                *(short4v*)dst = v;
                *(short4v*)(dst + 8) = z;
                *(short4v*)(dst + 16) = z;
                *(short4v*)(dst + 24) = z;
            }
        } else {
            // bf16 NHWC 32-ch input, staged in 8B chunks (72B stride is 8B-aligned)
            const short* inb = (const short*)inv + (size_t)img * HW * 32;
            for (int c = tid; c < RR * XX * 8; c += 256) {
                int p = c >> 3, cc = c & 7;
                int yy = p / XX, xx = p % XX, gy = gy0 + yy, gx = gx0 + xx;
                short4v v;
                if ((gy >= 0) & (gy < H) & (gx >= 0) & (gx < W))
                    v = *(const short4v*)(inb + ((size_t)gy * W + gx) * 32 + cc * 4);
                else { v[0] = v[1] = v[2] = v[3] = 0; }
                *(short4v*)(lds + p * PB + cc * 8) = v;
            }
        }
        __syncthreads();

#pragma unroll
        for (int s = 0; s < NS; ++s) {
            const int tap = s / ICS, hh = s % ICS;
            const int ky = tap / KS, kx = tap % KS;
            const char* ap = lds + ((w + ky) * XX + lx + kx) * PB + hh * 32 + lh * 16;
            union { short4v h[2]; short8v v; } u;
            u.h[0] = *(const short4v*)ap;
            u.h[1] = *(const short4v*)(ap + 8);
#pragma unroll
            for (int nt = 0; nt < NT; ++nt) {
                short8v bf = *(const short8v*)(wq + ((size_t)(s * NT + nt) * 64 + l) * 8);
                acc[nt] = __builtin_amdgcn_mfma_f32_32x32x16_bf16(u.v, bf, acc[nt], 0, 0, 0);
            }
        }
    }

    constexpr float MS = (NACC == 4) ? 0.25f : 1.f;
    const int y = yt * 4 + w;
    if (OMODE == 0) {
        const float bb = bias[lx];
        short* ob = (short*)outv + ((size_t)og * HW + (size_t)y * W + xt * 32) * 32 + lx;
#pragma unroll
        for (int r = 0; r < 16; ++r) {
            int row = (r & 3) + 8 * (r >> 2) + 4 * lh;   // x offset within tile
            float vv = acc[0][r] * MS + bb;
            if (RELU) vv = fmaxf(vv, 0.f);
            ob[(size_t)row * 32] = f2b(vv);
        }
    } else if (OMODE == 1) {
        short* ob = (short*)outv + ((size_t)og * HW + (size_t)y * W + xt * 32) * 64;
#pragma unroll
        for (int nt = 0; nt < NT; ++nt) {
            const int oc = nt * 32 + lx;
            const float bb = bias[oc];
#pragma unroll
            for (int r = 0; r < 16; ++r) {
                int row = (r & 3) + 8 * (r >> 2) + 4 * lh;
                ob[(size_t)row * 64 + oc] = f2b(acc[nt][r] + bb);
            }
        }
    } else {
        const int oc = lx;
        const float bb = bias[oc];
        float* ob = (float*)outv;
#pragma unroll
        for (int r = 0; r < 16; ++r) {
            int row = (r & 3) + 8 * (r >> 2) + 4 * lh;
            float vv = tanhf(acc[0][r] + bb);
            if (oc < 3)
                ob[(((size_t)og * 3 + oc) * H + y) * W + xt * 32 + row] = vv;
        }
    }
}

// ---------------- deformable conv via MFMA ----------------
// Wave = 32-pixel x-strip (one row) x 32 oc. GEMM: M=32 px, N=32 oc, K=800 (25 taps x 32 ic).
// Each lane bilinear-gathers its pixel's 8-ic slice per K-half, packs to bf16 (A-frag),
// B-frags precomputed. Same fragment layout as mconv_k.
__global__ __launch_bounds__(256) void deform_m_k(
    const short* __restrict__ xn,   // mean NHWC bf16 [4][HW][32]
    const short* __restrict__ offs, // NHWC bf16 [4][HW][64] (50 used)
    const short* __restrict__ wq,   // deform B-frags [50][64][8]
    const float* __restrict__ bias,
    short* __restrict__ out)        // NHWC bf16 [4][HW][32]
{
    const int tid = threadIdx.x, w = tid >> 6, l = tid & 63, lx = l & 31, lh = l >> 5;
    const int S = blockIdx.x * 4 + w;          // strip id, 3200 total
    const int x0 = (S % 5) * 32;
    const int y  = (S / 5) % H;
    const int img = S / 800;
    const int px = x0 + lx;

    const short* xb = xn + (size_t)img * HW * 32;
    const short* op = offs + ((size_t)img * HW + (size_t)y * W + px) * 64;

    f32x16 acc;
#pragma unroll
    for (int i = 0; i < 16; ++i) acc[i] = 0.f;

    for (int t = 0; t < 25; ++t) {
        const int ky = t / 5, kx = t % 5;
        unsigned int oo = *(const unsigned int*)(op + 2 * t);   // (dy,dx) bf16 pair
        float dy = b2f((short)(oo & 0xffff));
        float dx = b2f((short)(oo >> 16));
        float py  = (float)(y - 2 + ky) + dy;
        float pxf = (float)(px - 2 + kx) + dx;
        float fy = floorf(py), fx = floorf(pxf);
        float wy = py - fy, wx = pxf - fx;
        int iy = (int)fy, ix = (int)fx;

        float wgt[4]; const short* cp[4]; bool ok[4];
#pragma unroll
        for (int c = 0; c < 4; ++c) {
            int yy = iy + (c >> 1), xx = ix + (c & 1);
            ok[c] = (yy >= 0) & (yy < H) & (xx >= 0) & (xx < W);
            wgt[c] = ((c >> 1) ? wy : 1.f - wy) * ((c & 1) ? wx : 1.f - wx);
            cp[c] = xb + ((size_t)yy * W + xx) * 32;
        }

#pragma unroll
        for (int h = 0; h < 2; ++h) {
            const int ic0 = h * 16 + lh * 8;
            float va[8];
#pragma unroll
            for (int j = 0; j < 8; ++j) va[j] = 0.f;
#pragma unroll
            for (int c = 0; c < 4; ++c) {
                if (ok[c]) {
                    short8v g = *(const short8v*)(cp[c] + ic0);
#pragma unroll
                    for (int j = 0; j < 8; ++j) va[j] = fmaf(wgt[c], b2f(g[j]), va[j]);
                }
            }
            short8v u;
#pragma unroll
            for (int j = 0; j < 8; ++j) u[j] = f2b(va[j]);
            short8v bf = *(const short8v*)(wq + ((size_t)(t * 2 + h) * 64 + l) * 8);
            acc = __builtin_amdgcn_mfma_f32_32x32x16_bf16(u, bf, acc, 0, 0, 0);
        }
    }

    const float bb = bias[lx];
    short* ob = out + ((size_t)img * HW + (size_t)y * W + x0) * 32 + lx;
#pragma unroll
    for (int r = 0; r < 16; ++r) {
        int row = (r & 3) + 8 * (r >> 2) + 4 * lh;
        ob[(size_t)row * 32] = f2b(acc[r] + bb);
    }
}

// ---------------- launch ----------------
extern "C" void kernel_launch(void* const* d_in, const int* in_sizes, int n_in,
                              void* d_out, int out_size, void* d_ws, size_t ws_size,
                              hipStream_t stream)
{
    const float* rg  = (const float*)d_in[0];
    const float* w1  = (const float*)d_in[1];  const float* b1 = (const float*)d_in[2];
    const float* g1  = (const float*)d_in[3];  const float* be1 = (const float*)d_in[4];
    const float* m1  = (const float*)d_in[5];  const float* v1 = (const float*)d_in[6];
    const float* w2  = (const float*)d_in[7];  const float* b2 = (const float*)d_in[8];
    const float* g2  = (const float*)d_in[9];  const float* be2 = (const float*)d_in[10];
    const float* m2  = (const float*)d_in[11]; const float* v2 = (const float*)d_in[12];
    const float* w3  = (const float*)d_in[13]; const float* b3 = (const float*)d_in[14];
    const float* wo  = (const float*)d_in[15]; const float* bo = (const float*)d_in[16];
    const float* wd  = (const float*)d_in[17]; const float* bd = (const float*)d_in[18];
    const float* w4  = (const float*)d_in[19]; const float* b4 = (const float*)d_in[20];
    const float* g4  = (const float*)d_in[21]; const float* be4 = (const float*)d_in[22];
    const float* m4  = (const float*)d_in[23]; const float* v4 = (const float*)d_in[24];
    const float* w5  = (const float*)d_in[25]; const float* b5 = (const float*)d_in[26];

    short* q   = (short*)d_ws;
    float* fp  = (float*)((char*)d_ws + FPB);
    short* act = (short*)((char*)d_ws + ACTB);
    short* act1  = act + A1;
    short* act2  = act + A2;
    short* amean = act + AM;
    short* aoffs = act + AO;
    short* adf   = act + AD;
    short* a4o   = act + A4;

    prep_k<<<NPREP / 256, 256, 0, stream>>>(
        w1, b1, g1, be1, m1, v1, w2, b2, g2, be2, m2, v2, w3, b3,
        wo, bo, wd, bd, w4, b4, g4, be4, m4, v4, w5, b5, q, fp);

    // stage A (16 images)
    mconv_k<5, 1, 1, 1, 0, true,  true ><<<3200, 256, 0, stream>>>(rg,   q + Q1, fp + B1, act1);
    mconv_k<5, 2, 1, 1, 0, true,  false><<<3200, 256, 0, stream>>>(act1, q + Q2, fp + B2, act2);
    mconv_k<3, 2, 1, 4, 0, false, false><<< 800, 256, 0, stream>>>(act2, q + Q3, fp + B3, amean);

    // stage B (4 images)
    mconv_k<5, 2, 2, 1, 1, false, false><<< 800, 256, 0, stream>>>(amean, q + QO, fp + BO, aoffs);
    deform_m_k<<<800, 256, 0, stream>>>(amean, aoffs, q + QD, fp + BD, adf);
    mconv_k<3, 2, 1, 1, 0, true,  false><<< 800, 256, 0, stream>>>(adf,  q + Q4, fp + B4, a4o);
    mconv_k<3, 2, 1, 1, 2, false, false><<< 800, 256, 0, stream>>>(a4o,  q + Q5, fp + B5, d_out);
}

// Round 9
// 278.026 us; speedup vs baseline: 4.6564x; 1.0821x over previous
//
#include <hip/hip_runtime.h>
#include <hip/hip_bf16.h>

#define DI static __device__ __forceinline__

typedef __attribute__((ext_vector_type(8)))  short short8v;   // 8 bf16 = 4 VGPR (MFMA A/B frag)
typedef __attribute__((ext_vector_type(4)))  short short4v;   // 8B
typedef __attribute__((ext_vector_type(4)))  float float4v;
typedef __attribute__((ext_vector_type(16))) float f32x16;    // MFMA C/D frag

namespace {
constexpr int H = 160, W = 160, HW = H * W;

// ---- bf16 fragment region (short offsets, base = d_ws + 0) ----
constexpr int Q1 = 0;        // conv1: 25 ksteps * 64 * 8 = 12800
constexpr int Q2 = 12800;    // conv2: 50 * 512 = 25600
constexpr int Q3 = 38400;    // conv3: 18 * 512 = 9216
constexpr int QO = 47616;    // offs : 50 * 2 * 512 = 51200
constexpr int Q4 = 98816;    // conv4: 18 * 512
constexpr int Q5 = 108032;   // conv5: 18 * 512
constexpr int QD = 117248;   // deform: 50 * 512 = 25600
constexpr int QEND = 142848;

// ---- fp32 region (byte offset, float offsets within) ----
constexpr size_t FPB = 285696;            // = QEND*2
constexpr int B1 = 0, B2 = 32, B3 = 64, BO = 96, BD = 160, B4 = 192, B5 = 224;
constexpr int NFP = 256;

// ---- activation region (byte offset, short offsets within) ----
constexpr size_t ACTB = 286720;           // FPB + NFP*4
constexpr size_t A1 = 0;                  // conv1 out: 16*HW*32 bf16
constexpr size_t A2 = 13107200;           // conv2 out
constexpr size_t AM = 26214400;           // mean: 4*HW*32
constexpr size_t AO = 29491200;           // offsets: 4*HW*64 (padded 50->64)
constexpr size_t AD = 36044800;           // deform out: 4*HW*32
constexpr size_t A4 = 39321600;           // conv4 out

constexpr int NPREP = QEND + 256;         // 143104 = 559*256 exactly
} // namespace

DI float b2f(short s) {
    unsigned int u = ((unsigned int)(unsigned short)s) << 16;
    float f; __builtin_memcpy(&f, &u, 4); return f;
}
DI short f2b(float f) {
    __hip_bfloat16 h = __float2bfloat16(f);
    short s; __builtin_memcpy(&s, &h, 2); return s;
}

// ---------------- prep: build per-lane MFMA B-fragments + BN fold + biases ----------------
// frag layout: [s][nt][lane][8] bf16, s = (ky*KS+kx)*ICS + h.
// B element: col oc = nt*32 + (lane&31); k = (lane>>5)*8 + j; ic = h*16 + k.
DI void fragw(int j, const float* __restrict__ w, const float* g, const float* v,
              int IC, int KS, int ICS, int NT, int OC, short* __restrict__ dst) {
    int q = j & 7;
    int l = (j >> 3) & 63;
    int rest = j >> 9;            // s*NT + nt
    int nt = rest % NT, s = rest / NT;
    int h = s % ICS, tap = s / ICS;
    int oc = nt * 32 + (l & 31);
    int ic = h * 16 + (l >> 5) * 8 + q;
    float val = 0.f;
    if (oc < OC && ic < IC) {
        val = w[((size_t)(oc * IC + ic)) * (KS * KS) + tap];
        if (g) val *= g[oc] * rsqrtf(v[oc] + 1e-5f);
    }
    dst[j] = f2b(val);
}

__global__ void prep_k(
    const float* __restrict__ w1, const float* __restrict__ b1, const float* __restrict__ g1,
    const float* __restrict__ be1, const float* __restrict__ m1, const float* __restrict__ v1,
    const float* __restrict__ w2, const float* __restrict__ b2, const float* __restrict__ g2,
    const float* __restrict__ be2, const float* __restrict__ m2, const float* __restrict__ v2,
    const float* __restrict__ w3, const float* __restrict__ b3,
    const float* __restrict__ wo, const float* __restrict__ bo,
    const float* __restrict__ wd, const float* __restrict__ bd,
    const float* __restrict__ w4, const float* __restrict__ b4, const float* __restrict__ g4,
    const float* __restrict__ be4, const float* __restrict__ m4, const float* __restrict__ v4,
    const float* __restrict__ w5, const float* __restrict__ b5,
    short* __restrict__ q, float* __restrict__ fp)
{
    int j = blockIdx.x * 256 + threadIdx.x;
    if (j >= NPREP) return;
    if (j < Q2)   { fragw(j - Q1, w1, g1, v1, 3, 5, 1, 1, 32, q + Q1); return; }
    if (j < Q3)   { fragw(j - Q2, w2, g2, v2, 32, 5, 2, 1, 32, q + Q2); return; }
    if (j < QO)   { fragw(j - Q3, w3, nullptr, nullptr, 32, 3, 2, 1, 32, q + Q3); return; }
    if (j < Q4)   { fragw(j - QO, wo, nullptr, nullptr, 32, 5, 2, 2, 50, q + QO); return; }
    if (j < Q5)   { fragw(j - Q4, w4, g4, v4, 32, 3, 2, 1, 32, q + Q4); return; }
    if (j < QD)   { fragw(j - Q5, w5, nullptr, nullptr, 32, 3, 2, 1, 3, q + Q5); return; }
    if (j < QEND) { fragw(j - QD, wd, nullptr, nullptr, 32, 5, 2, 1, 32, q + QD); return; }
    j -= QEND;
    if (j < 32) { float s = g1[j] * rsqrtf(v1[j] + 1e-5f); fp[B1 + j] = s * (b1[j] - m1[j]) + be1[j]; return; } j -= 32;
    if (j < 32) { float s = g2[j] * rsqrtf(v2[j] + 1e-5f); fp[B2 + j] = s * (b2[j] - m2[j]) + be2[j]; return; } j -= 32;
    if (j < 32) { fp[B3 + j] = b3[j]; return; } j -= 32;
    if (j < 64) { fp[BO + j] = (j < 50) ? bo[j] : 0.f; return; } j -= 64;
    if (j < 32) { fp[BD + j] = bd[j]; return; } j -= 32;
    if (j < 32) { float s = g4[j] * rsqrtf(v4[j] + 1e-5f); fp[B4 + j] = s * (b4[j] - m4[j]) + be4[j]; return; } j -= 32;
    if (j < 32) { fp[B5 + j] = (j < 3) ? b5[j] : 0.f; return; }
}

// ---------------- MFMA implicit-GEMM conv ----------------
// Block = 4 waves; wave w computes output row y = yt*4+w, 32 x-positions, 32*NT oc.
// A from LDS (NHWC tile, 72B pixel stride -> conflict-free ds_read_b64 pairs);
// B from global precomputed frags (16B/lane, coalesced, L1-resident).
// OMODE: 0 = bf16 NHWC stride 32; 1 = bf16 NHWC stride 64 (offsets); 2 = tanh fp32 NCHW oc<3.
template<int KS, int ICS, int NT, int NACC, int OMODE, bool RELU, bool IN3>
__global__ __launch_bounds__(256) void mconv_k(
    const void* __restrict__ inv, const short* __restrict__ wq,
    const float* __restrict__ bias, void* __restrict__ outv)
{
    constexpr int PAD = KS / 2, RR = 3 + KS, XX = 31 + KS;
    constexpr int PB = IN3 ? 40 : 72;      // pixel stride bytes (bank-spread, 8B-aligned)
    constexpr int NS = KS * KS * ICS;      // K-steps per image
    __shared__ __align__(16) char lds[RR * XX * PB];

    const int tid = threadIdx.x, w = tid >> 6, l = tid & 63, lx = l & 31, lh = l >> 5;
    const int b = blockIdx.x;
    const int xt = b % 5, yt = (b / 5) % 40, og = b / 200;
    const int gx0 = xt * 32 - PAD, gy0 = yt * 4 - PAD;

    f32x16 acc[NT];
#pragma unroll
    for (int nt = 0; nt < NT; ++nt)
#pragma unroll
        for (int i = 0; i < 16; ++i) acc[nt][i] = 0.f;

    for (int n = 0; n < NACC; ++n) {
        if (n) __syncthreads();
        const int img = og * NACC + n;
        if (IN3) {
            // fp32 NCHW 3-ch input -> bf16, ic padded to 16
            const float* inb = (const float*)inv + (size_t)img * 3 * HW;
            for (int p = tid; p < RR * XX; p += 256) {
                int yy = p / XX, xx = p % XX, gy = gy0 + yy, gx = gx0 + xx;
                bool ok = (gy >= 0) & (gy < H) & (gx >= 0) & (gx < W);
                size_t o = (size_t)gy * W + gx;
                short4v v; v[0] = ok ? f2b(inb[o]) : (short)0;
                v[1] = ok ? f2b(inb[HW + o]) : (short)0;
                v[2] = ok ? f2b(inb[2 * HW + o]) : (short)0; v[3] = 0;
                short4v z; z[0] = z[1] = z[2] = z[3] = 0;
                char* dst = lds + p * PB;
                *(short4v*)dst = v;
                *(short4v*)(dst + 8) = z;
                *(short4v*)(dst + 16) = z;
                *(short4v*)(dst + 24) = z;
            }
        } else {
            // bf16 NHWC 32-ch input, staged in 8B chunks (72B stride is 8B-aligned)
            const short* inb = (const short*)inv + (size_t)img * HW * 32;
            for (int c = tid; c < RR * XX * 8; c += 256) {
                int p = c >> 3, cc = c & 7;
                int yy = p / XX, xx = p % XX, gy = gy0 + yy, gx = gx0 + xx;
                short4v v;
                if ((gy >= 0) & (gy < H) & (gx >= 0) & (gx < W))
                    v = *(const short4v*)(inb + ((size_t)gy * W + gx) * 32 + cc * 4);
                else { v[0] = v[1] = v[2] = v[3] = 0; }
                *(short4v*)(lds + p * PB + cc * 8) = v;
            }
        }
        __syncthreads();

#pragma unroll
        for (int s = 0; s < NS; ++s) {
            const int tap = s / ICS, hh = s % ICS;
            const int ky = tap / KS, kx = tap % KS;
            const char* ap = lds + ((w + ky) * XX + lx + kx) * PB + hh * 32 + lh * 16;
            union { short4v h[2]; short8v v; } u;
            u.h[0] = *(const short4v*)ap;
            u.h[1] = *(const short4v*)(ap + 8);
#pragma unroll
            for (int nt = 0; nt < NT; ++nt) {
                short8v bf = *(const short8v*)(wq + ((size_t)(s * NT + nt) * 64 + l) * 8);
                acc[nt] = __builtin_amdgcn_mfma_f32_32x32x16_bf16(u.v, bf, acc[nt], 0, 0, 0);
            }
        }
    }

    constexpr float MS = (NACC == 4) ? 0.25f : 1.f;
    const int y = yt * 4 + w;
    if (OMODE == 0) {
        const float bb = bias[lx];
        short* ob = (short*)outv + ((size_t)og * HW + (size_t)y * W + xt * 32) * 32 + lx;
#pragma unroll
        for (int r = 0; r < 16; ++r) {
            int row = (r & 3) + 8 * (r >> 2) + 4 * lh;   // x offset within tile
            float vv = acc[0][r] * MS + bb;
            if (RELU) vv = fmaxf(vv, 0.f);
            ob[(size_t)row * 32] = f2b(vv);
        }
    } else if (OMODE == 1) {
        short* ob = (short*)outv + ((size_t)og * HW + (size_t)y * W + xt * 32) * 64;
#pragma unroll
        for (int nt = 0; nt < NT; ++nt) {
            const int oc = nt * 32 + lx;
            const float bb = bias[oc];
#pragma unroll
            for (int r = 0; r < 16; ++r) {
                int row = (r & 3) + 8 * (r >> 2) + 4 * lh;
                ob[(size_t)row * 64 + oc] = f2b(acc[nt][r] + bb);
            }
        }
    } else {
        const int oc = lx;
        const float bb = bias[oc];
        float* ob = (float*)outv;
#pragma unroll
        for (int r = 0; r < 16; ++r) {
            int row = (r & 3) + 8 * (r >> 2) + 4 * lh;
            float vv = tanhf(acc[0][r] + bb);
            if (oc < 3)
                ob[(((size_t)og * 3 + oc) * H + y) * W + xt * 32 + row] = vv;
        }
    }
}

// ---------------- deformable conv via MFMA, tap-split across 4 waves ----------------
// Block = 4 waves, ONE 32-pixel strip. Wave w handles taps t = w, w+4, ... (7/6/6/6).
// Each wave accumulates partial f32x16; waves 1-3 spill to LDS, wave 0 reduces+stores.
// Grid 3200 blocks = 12.5 blocks/CU -> 8 waves/SIMD occupancy (latency hiding).
__global__ __launch_bounds__(256) void deform_m_k(
    const short* __restrict__ xn,   // mean NHWC bf16 [4][HW][32]
    const short* __restrict__ offs, // NHWC bf16 [4][HW][64] (50 used)
    const short* __restrict__ wq,   // deform B-frags [50][64][8]
    const float* __restrict__ bias,
    short* __restrict__ out)        // NHWC bf16 [4][HW][32]
{
    __shared__ float red[3][64][16];   // 12 KB partial-acc spill

    const int tid = threadIdx.x, w = tid >> 6, l = tid & 63, lx = l & 31, lh = l >> 5;
    const int S = blockIdx.x;          // strip id, 3200 total
    const int x0 = (S % 5) * 32;
    const int y  = (S / 5) % H;
    const int img = S / 800;
    const int px = x0 + lx;

    const short* xb = xn + (size_t)img * HW * 32;
    const short* op = offs + ((size_t)img * HW + (size_t)y * W + px) * 64;

    f32x16 acc;
#pragma unroll
    for (int i = 0; i < 16; ++i) acc[i] = 0.f;

    for (int t = w; t < 25; t += 4) {
        const int ky = t / 5, kx = t % 5;
        unsigned int oo = *(const unsigned int*)(op + 2 * t);   // (dy,dx) bf16 pair
        float dy = b2f((short)(oo & 0xffff));
        float dx = b2f((short)(oo >> 16));
        float py  = (float)(y - 2 + ky) + dy;
        float pxf = (float)(px - 2 + kx) + dx;
        float fy = floorf(py), fx = floorf(pxf);
        float wy = py - fy, wx = pxf - fx;
        int iy = (int)fy, ix = (int)fx;

        float wgt[4]; const short* cp[4]; bool ok[4];
#pragma unroll
        for (int c = 0; c < 4; ++c) {
            int yy = iy + (c >> 1), xx = ix + (c & 1);
            ok[c] = (yy >= 0) & (yy < H) & (xx >= 0) & (xx < W);
            wgt[c] = ((c >> 1) ? wy : 1.f - wy) * ((c & 1) ? wx : 1.f - wx);
            cp[c] = xb + ((size_t)yy * W + xx) * 32;
        }

#pragma unroll
        for (int h = 0; h < 2; ++h) {
            const int ic0 = h * 16 + lh * 8;
            float va[8];
#pragma unroll
            for (int j = 0; j < 8; ++j) va[j] = 0.f;
#pragma unroll
            for (int c = 0; c < 4; ++c) {
                if (ok[c]) {
                    short8v g = *(const short8v*)(cp[c] + ic0);
#pragma unroll
                    for (int j = 0; j < 8; ++j) va[j] = fmaf(wgt[c], b2f(g[j]), va[j]);
                }
            }
            short8v u;
#pragma unroll
            for (int j = 0; j < 8; ++j) u[j] = f2b(va[j]);
            short8v bf = *(const short8v*)(wq + ((size_t)(t * 2 + h) * 64 + l) * 8);
            acc = __builtin_amdgcn_mfma_f32_32x32x16_bf16(u, bf, acc, 0, 0, 0);
        }
    }

    if (w) {
        float* rp = &red[w - 1][l][0];
#pragma unroll
        for (int r4 = 0; r4 < 4; ++r4) {
            float4v v; v[0] = acc[r4 * 4]; v[1] = acc[r4 * 4 + 1];
            v[2] = acc[r4 * 4 + 2]; v[3] = acc[r4 * 4 + 3];
            *(float4v*)(rp + r4 * 4) = v;
        }
    }
    __syncthreads();
    if (w == 0) {
#pragma unroll
        for (int j = 0; j < 3; ++j) {
            const float* rp = &red[j][l][0];
#pragma unroll
            for (int r4 = 0; r4 < 4; ++r4) {
                float4v v = *(const float4v*)(rp + r4 * 4);
                acc[r4 * 4] += v[0]; acc[r4 * 4 + 1] += v[1];
                acc[r4 * 4 + 2] += v[2]; acc[r4 * 4 + 3] += v[3];
            }
        }
        const float bb = bias[lx];
        short* ob = out + ((size_t)img * HW + (size_t)y * W + x0) * 32 + lx;
#pragma unroll
        for (int r = 0; r < 16; ++r) {
            int row = (r & 3) + 8 * (r >> 2) + 4 * lh;
            ob[(size_t)row * 32] = f2b(acc[r] + bb);
        }
    }
}

// ---------------- launch ----------------
extern "C" void kernel_launch(void* const* d_in, const int* in_sizes, int n_in,
                              void* d_out, int out_size, void* d_ws, size_t ws_size,
                              hipStream_t stream)
{
    const float* rg  = (const float*)d_in[0];
    const float* w1  = (const float*)d_in[1];  const float* b1 = (const float*)d_in[2];
    const float* g1  = (const float*)d_in[3];  const float* be1 = (const float*)d_in[4];
    const float* m1  = (const float*)d_in[5];  const float* v1 = (const float*)d_in[6];
    const float* w2  = (const float*)d_in[7];  const float* b2 = (const float*)d_in[8];
    const float* g2  = (const float*)d_in[9];  const float* be2 = (const float*)d_in[10];
    const float* m2  = (const float*)d_in[11]; const float* v2 = (const float*)d_in[12];
    const float* w3  = (const float*)d_in[13]; const float* b3 = (const float*)d_in[14];
    const float* wo  = (const float*)d_in[15]; const float* bo = (const float*)d_in[16];
    const float* wd  = (const float*)d_in[17]; const float* bd = (const float*)d_in[18];
    const float* w4  = (const float*)d_in[19]; const float* b4 = (const float*)d_in[20];
    const float* g4  = (const float*)d_in[21]; const float* be4 = (const float*)d_in[22];
    const float* m4  = (const float*)d_in[23]; const float* v4 = (const float*)d_in[24];
    const float* w5  = (const float*)d_in[25]; const float* b5 = (const float*)d_in[26];

    short* q   = (short*)d_ws;
    float* fp  = (float*)((char*)d_ws + FPB);
    short* act = (short*)((char*)d_ws + ACTB);
    short* act1  = act + A1;
    short* act2  = act + A2;
    short* amean = act + AM;
    short* aoffs = act + AO;
    short* adf   = act + AD;
    short* a4o   = act + A4;

    prep_k<<<NPREP / 256, 256, 0, stream>>>(
        w1, b1, g1, be1, m1, v1, w2, b2, g2, be2, m2, v2, w3, b3,
        wo, bo, wd, bd, w4, b4, g4, be4, m4, v4, w5, b5, q, fp);

    // stage A (16 images)
    mconv_k<5, 1, 1, 1, 0, true,  true ><<<3200, 256, 0, stream>>>(rg,   q + Q1, fp + B1, act1);
    mconv_k<5, 2, 1, 1, 0, true,  false><<<3200, 256, 0, stream>>>(act1, q + Q2, fp + B2, act2);
    mconv_k<3, 2, 1, 4, 0, false, false><<< 800, 256, 0, stream>>>(act2, q + Q3, fp + B3, amean);

    // stage B (4 images)
    mconv_k<5, 2, 2, 1, 1, false, false><<< 800, 256, 0, stream>>>(amean, q + QO, fp + BO, aoffs);
    deform_m_k<<<3200, 256, 0, stream>>>(amean, aoffs, q + QD, fp + BD, adf);
    mconv_k<3, 2, 1, 1, 0, true,  false><<< 800, 256, 0, stream>>>(adf,  q + Q4, fp + B4, a4o);
    mconv_k<3, 2, 1, 1, 2, false, false><<< 800, 256, 0, stream>>>(a4o,  q + Q5, fp + B5, d_out);
}

// Round 13
// 267.053 us; speedup vs baseline: 4.8477x; 1.0411x over previous
//
#include <hip/hip_runtime.h>
#include <hip/hip_bf16.h>

#define DI static __device__ __forceinline__

typedef __attribute__((ext_vector_type(8)))  short short8v;   // 8 bf16 = 4 VGPR (MFMA A/B frag)
typedef __attribute__((ext_vector_type(4)))  short short4v;   // 8B
typedef __attribute__((ext_vector_type(4)))  float float4v;
typedef __attribute__((ext_vector_type(16))) float f32x16;    // MFMA C/D frag

namespace {
constexpr int H = 160, W = 160, HW = H * W;

// ---- bf16 fragment region (short offsets, base = d_ws + 0) ----
constexpr int Q1 = 0;        // conv1: 25 ksteps * 64 * 8 = 12800
constexpr int Q2 = 12800;    // conv2: 50 * 512 = 25600
constexpr int Q3 = 38400;    // conv3: 18 * 512 = 9216
constexpr int QO = 47616;    // offs : 50 * 2 * 512 = 51200
constexpr int Q4 = 98816;    // conv4: 18 * 512
constexpr int Q5 = 108032;   // conv5: 18 * 512
constexpr int QD = 117248;   // deform: 50 * 512 = 25600
constexpr int QEND = 142848;

// ---- fp32 region (byte offset, float offsets within) ----
constexpr size_t FPB = 285696;            // = QEND*2
constexpr int B1 = 0, B2 = 32, B3 = 64, BO = 96, BD = 160, B4 = 192, B5 = 224;
constexpr int NFP = 256;

// ---- activation region (byte offset, short offsets within) ----
constexpr size_t ACTB = 286720;           // FPB + NFP*4
constexpr size_t A1 = 0;                  // conv1 out: 16*HW*32 bf16
constexpr size_t A2 = 13107200;           // conv2 out
constexpr size_t AM = 26214400;           // mean: 4*HW*32
constexpr size_t AO = 29491200;           // offsets: 4*HW*64, phase-grouped (see perm)
constexpr size_t AD = 36044800;           // deform out: 4*HW*32
constexpr size_t A4 = 39321600;           // conv4 out

constexpr int NPREP = QEND + 256;         // 143104 = 559*256 exactly
} // namespace

DI float b2f(short s) {
    unsigned int u = ((unsigned int)(unsigned short)s) << 16;
    float f; __builtin_memcpy(&f, &u, 4); return f;
}
DI short f2b(float f) {
    __hip_bfloat16 h = __float2bfloat16(f);
    short s; __builtin_memcpy(&s, &h, 2); return s;
}

// offsets channel permutation: group taps by phase p = t%4 so deform wave w
// reads its 7 (dy,dx) pairs contiguously at +w*16 shorts (16B-aligned).
// oc<50: t=oc>>1, d=oc&1 -> newc = (t%4)*16 + (t/4)*2 + d.
// oc>=50 (pad): fill unused slots {14,15, 28..31, 44..47, 60..63}.
DI int offs_perm(int oc) {
    if (oc < 50) {
        int t = oc >> 1, d = oc & 1;
        return (t & 3) * 16 + (t >> 2) * 2 + d;
    }
    int i = oc - 50;
    if (i < 2)  return 14 + i;
    if (i < 6)  return 28 + (i - 2);
    if (i < 10) return 44 + (i - 6);
    return 60 + (i - 10);
}

// ---------------- prep: build per-lane MFMA B-fragments + BN fold + biases ----------------
// frag layout: [s][nt][lane][8] bf16, s = (ky*KS+kx)*ICS + h.
// B element: col oc = nt*32 + (lane&31); k = (lane>>5)*8 + j; ic = h*16 + k.
DI void fragw(int j, const float* __restrict__ w, const float* g, const float* v,
              int IC, int KS, int ICS, int NT, int OC, short* __restrict__ dst) {
    int q = j & 7;
    int l = (j >> 3) & 63;
    int rest = j >> 9;            // s*NT + nt
    int nt = rest % NT, s = rest / NT;
    int h = s % ICS, tap = s / ICS;
    int oc = nt * 32 + (l & 31);
    int ic = h * 16 + (l >> 5) * 8 + q;
    float val = 0.f;
    if (oc < OC && ic < IC) {
        val = w[((size_t)(oc * IC + ic)) * (KS * KS) + tap];
        if (g) val *= g[oc] * rsqrtf(v[oc] + 1e-5f);
    }
    dst[j] = f2b(val);
}

__global__ void prep_k(
    const float* __restrict__ w1, const float* __restrict__ b1, const float* __restrict__ g1,
    const float* __restrict__ be1, const float* __restrict__ m1, const float* __restrict__ v1,
    const float* __restrict__ w2, const float* __restrict__ b2, const float* __restrict__ g2,
    const float* __restrict__ be2, const float* __restrict__ m2, const float* __restrict__ v2,
    const float* __restrict__ w3, const float* __restrict__ b3,
    const float* __restrict__ wo, const float* __restrict__ bo,
    const float* __restrict__ wd, const float* __restrict__ bd,
    const float* __restrict__ w4, const float* __restrict__ b4, const float* __restrict__ g4,
    const float* __restrict__ be4, const float* __restrict__ m4, const float* __restrict__ v4,
    const float* __restrict__ w5, const float* __restrict__ b5,
    short* __restrict__ q, float* __restrict__ fp)
{
    int j = blockIdx.x * 256 + threadIdx.x;
    if (j >= NPREP) return;
    if (j < Q2)   { fragw(j - Q1, w1, g1, v1, 3, 5, 1, 1, 32, q + Q1); return; }
    if (j < Q3)   { fragw(j - Q2, w2, g2, v2, 32, 5, 2, 1, 32, q + Q2); return; }
    if (j < QO)   { fragw(j - Q3, w3, nullptr, nullptr, 32, 3, 2, 1, 32, q + Q3); return; }
    if (j < Q4)   { fragw(j - QO, wo, nullptr, nullptr, 32, 5, 2, 2, 50, q + QO); return; }
    if (j < Q5)   { fragw(j - Q4, w4, g4, v4, 32, 3, 2, 1, 32, q + Q4); return; }
    if (j < QD)   { fragw(j - Q5, w5, nullptr, nullptr, 32, 3, 2, 1, 3, q + Q5); return; }
    if (j < QEND) { fragw(j - QD, wd, nullptr, nullptr, 32, 5, 2, 1, 32, q + QD); return; }
    j -= QEND;
    if (j < 32) { float s = g1[j] * rsqrtf(v1[j] + 1e-5f); fp[B1 + j] = s * (b1[j] - m1[j]) + be1[j]; return; } j -= 32;
    if (j < 32) { float s = g2[j] * rsqrtf(v2[j] + 1e-5f); fp[B2 + j] = s * (b2[j] - m2[j]) + be2[j]; return; } j -= 32;
    if (j < 32) { fp[B3 + j] = b3[j]; return; } j -= 32;
    if (j < 64) { fp[BO + j] = (j < 50) ? bo[j] : 0.f; return; } j -= 64;
    if (j < 32) { fp[BD + j] = bd[j]; return; } j -= 32;
    if (j < 32) { float s = g4[j] * rsqrtf(v4[j] + 1e-5f); fp[B4 + j] = s * (b4[j] - m4[j]) + be4[j]; return; } j -= 32;
    if (j < 32) { fp[B5 + j] = (j < 3) ? b5[j] : 0.f; return; }
}

// ---------------- MFMA implicit-GEMM conv ----------------
// Block = 4 waves; wave w computes output row y = yt*4+w, 32 x-positions, 32*NT oc.
// A from LDS (NHWC tile, 72B pixel stride -> conflict-free ds_read_b64 pairs);
// B from global precomputed frags (16B/lane, coalesced, L1-resident).
// OMODE: 0 = bf16 NHWC stride 32; 1 = bf16 NHWC stride 64 phase-grouped offsets;
//        2 = tanh fp32 NCHW oc<3.
template<int KS, int ICS, int NT, int NACC, int OMODE, bool RELU, bool IN3>
__global__ __launch_bounds__(256) void mconv_k(
    const void* __restrict__ inv, const short* __restrict__ wq,
    const float* __restrict__ bias, void* __restrict__ outv)
{
    constexpr int PAD = KS / 2, RR = 3 + KS, XX = 31 + KS;
    constexpr int PB = IN3 ? 40 : 72;      // pixel stride bytes (bank-spread, 8B-aligned)
    constexpr int NS = KS * KS * ICS;      // K-steps per image
    __shared__ __align__(16) char lds[RR * XX * PB];

    const int tid = threadIdx.x, w = tid >> 6, l = tid & 63, lx = l & 31, lh = l >> 5;
    const int b = blockIdx.x;
    const int xt = b % 5, yt = (b / 5) % 40, og = b / 200;
    const int gx0 = xt * 32 - PAD, gy0 = yt * 4 - PAD;

    f32x16 acc[NT];
#pragma unroll
    for (int nt = 0; nt < NT; ++nt)
#pragma unroll
        for (int i = 0; i < 16; ++i) acc[nt][i] = 0.f;

    for (int n = 0; n < NACC; ++n) {
        if (n) __syncthreads();
        const int img = og * NACC + n;
        if (IN3) {
            // fp32 NCHW 3-ch input -> bf16, ic padded to 16
            const float* inb = (const float*)inv + (size_t)img * 3 * HW;
            for (int p = tid; p < RR * XX; p += 256) {
                int yy = p / XX, xx = p % XX, gy = gy0 + yy, gx = gx0 + xx;
                bool ok = (gy >= 0) & (gy < H) & (gx >= 0) & (gx < W);
                size_t o = (size_t)gy * W + gx;
                short4v v; v[0] = ok ? f2b(inb[o]) : (short)0;
                v[1] = ok ? f2b(inb[HW + o]) : (short)0;
                v[2] = ok ? f2b(inb[2 * HW + o]) : (short)0; v[3] = 0;
                short4v z; z[0] = z[1] = z[2] = z[3] = 0;
                char* dst = lds + p * PB;
                *(short4v*)dst = v;
                *(short4v*)(dst + 8) = z;
                *(short4v*)(dst + 16) = z;
                *(short4v*)(dst + 24) = z;
            }
        } else {
            // bf16 NHWC 32-ch input, staged in 8B chunks (72B stride is 8B-aligned)
            const short* inb = (const short*)inv + (size_t)img * HW * 32;
            for (int c = tid; c < RR * XX * 8; c += 256) {
                int p = c >> 3, cc = c & 7;
                int yy = p / XX, xx = p % XX, gy = gy0 + yy, gx = gx0 + xx;
                short4v v;
                if ((gy >= 0) & (gy < H) & (gx >= 0) & (gx < W))
                    v = *(const short4v*)(inb + ((size_t)gy * W + gx) * 32 + cc * 4);
                else { v[0] = v[1] = v[2] = v[3] = 0; }
                *(short4v*)(lds + p * PB + cc * 8) = v;
            }
        }
        __syncthreads();

#pragma unroll
        for (int s = 0; s < NS; ++s) {
            const int tap = s / ICS, hh = s % ICS;
            const int ky = tap / KS, kx = tap % KS;
            const char* ap = lds + ((w + ky) * XX + lx + kx) * PB + hh * 32 + lh * 16;
            union { short4v h[2]; short8v v; } u;
            u.h[0] = *(const short4v*)ap;
            u.h[1] = *(const short4v*)(ap + 8);
#pragma unroll
            for (int nt = 0; nt < NT; ++nt) {
                short8v bf = *(const short8v*)(wq + ((size_t)(s * NT + nt) * 64 + l) * 8);
                acc[nt] = __builtin_amdgcn_mfma_f32_32x32x16_bf16(u.v, bf, acc[nt], 0, 0, 0);
            }
        }
    }

    constexpr float MS = (NACC == 4) ? 0.25f : 1.f;
    const int y = yt * 4 + w;
    if (OMODE == 0) {
        const float bb = bias[lx];
        short* ob = (short*)outv + ((size_t)og * HW + (size_t)y * W + xt * 32) * 32 + lx;
#pragma unroll
        for (int r = 0; r < 16; ++r) {
            int row = (r & 3) + 8 * (r >> 2) + 4 * lh;   // x offset within tile
            float vv = acc[0][r] * MS + bb;
            if (RELU) vv = fmaxf(vv, 0.f);
            ob[(size_t)row * 32] = f2b(vv);
        }
    } else if (OMODE == 1) {
        short* ob = (short*)outv + ((size_t)og * HW + (size_t)y * W + xt * 32) * 64;
#pragma unroll
        for (int nt = 0; nt < NT; ++nt) {
            const int oc = nt * 32 + lx;
            const float bb = bias[oc];
            const int nc = offs_perm(oc);          // phase-grouped channel
#pragma unroll
            for (int r = 0; r < 16; ++r) {
                int row = (r & 3) + 8 * (r >> 2) + 4 * lh;
                ob[(size_t)row * 64 + nc] = f2b(acc[nt][r] + bb);
            }
        }
    } else {
        const int oc = lx;
        const float bb = bias[oc];
        float* ob = (float*)outv;
#pragma unroll
        for (int r = 0; r < 16; ++r) {
            int row = (r & 3) + 8 * (r >> 2) + 4 * lh;
            float vv = tanhf(acc[0][r] + bb);
            if (oc < 3)
                ob[(((size_t)og * 3 + oc) * H + y) * W + xt * 32 + row] = vv;
        }
    }
}

// ---------------- deformable conv via MFMA, tap-split across 4 waves ----------------
// Block = 4 waves, ONE 32-pixel strip. Wave w handles taps t = 4*tt+w (7/6/6/6),
// compile-time unrolled for ILP. Offsets are phase-grouped: wave w's 7 (dy,dx)
// pairs are contiguous at +w*16 shorts (two aligned 16B loads).
// Partial f32x16 reduce via lane-major LDS [3][16][64] (conflict-free).
__global__ __launch_bounds__(256) void deform_m_k(
    const short* __restrict__ xn,   // mean NHWC bf16 [4][HW][32]
    const short* __restrict__ offs, // phase-grouped bf16 [4][HW][64]
    const short* __restrict__ wq,   // deform B-frags [50][64][8]
    const float* __restrict__ bias,
    short* __restrict__ out)        // NHWC bf16 [4][HW][32]
{
    __shared__ float red[3 * 16 * 64];   // 12 KB, lane-major

    const int tid = threadIdx.x, w = tid >> 6, l = tid & 63, lx = l & 31, lh = l >> 5;
    const int S = blockIdx.x;          // strip id, 3200 total
    const int x0 = (S % 5) * 32;
    const int y  = (S / 5) % H;
    const int img = S / 800;
    const int px = x0 + lx;

    const short* xb = xn + (size_t)img * HW * 32;
    const short* op2 = offs + ((size_t)img * HW + (size_t)y * W + px) * 64 + w * 16;

    union { short8v v2[2]; short s[16]; } pp;
    pp.v2[0] = *(const short8v*)(op2);
    pp.v2[1] = *(const short8v*)(op2 + 8);

    f32x16 acc;
#pragma unroll
    for (int i = 0; i < 16; ++i) acc[i] = 0.f;

#pragma unroll
    for (int tt = 0; tt < 7; ++tt) {
        const int t = 4 * tt + w;
        if (t < 25) {
            const int ky = t / 5, kx = t % 5;
            float dy = b2f(pp.s[2 * tt]);
            float dx = b2f(pp.s[2 * tt + 1]);
            float py  = (float)(y - 2 + ky) + dy;
            float pxf = (float)(px - 2 + kx) + dx;
            float fy = floorf(py), fx = floorf(pxf);
            float wy = py - fy, wx = pxf - fx;
            int iy = (int)fy, ix = (int)fx;

            float wgt[4]; const short* cp[4]; bool ok[4];
#pragma unroll
            for (int c = 0; c < 4; ++c) {
                int yy = iy + (c >> 1), xx = ix + (c & 1);
                ok[c] = (yy >= 0) & (yy < H) & (xx >= 0) & (xx < W);
                wgt[c] = ((c >> 1) ? wy : 1.f - wy) * ((c & 1) ? wx : 1.f - wx);
                cp[c] = xb + ((size_t)yy * W + xx) * 32;
            }

#pragma unroll
            for (int h = 0; h < 2; ++h) {
                const int ic0 = h * 16 + lh * 8;
                float va[8];
#pragma unroll
                for (int j = 0; j < 8; ++j) va[j] = 0.f;
#pragma unroll
                for (int c = 0; c < 4; ++c) {
                    if (ok[c]) {
                        short8v g = *(const short8v*)(cp[c] + ic0);
#pragma unroll
                        for (int j = 0; j < 8; ++j) va[j] = fmaf(wgt[c], b2f(g[j]), va[j]);
                    }
                }
                short8v u;
#pragma unroll
                for (int j = 0; j < 8; ++j) u[j] = f2b(va[j]);
                short8v bf = *(const short8v*)(wq + ((size_t)(t * 2 + h) * 64 + l) * 8);
                acc = __builtin_amdgcn_mfma_f32_32x32x16_bf16(u, bf, acc, 0, 0, 0);
            }
        }
    }

    if (w) {
        float* rp = &red[(w - 1) * 16 * 64 + l];
#pragma unroll
        for (int r = 0; r < 16; ++r) rp[r * 64] = acc[r];   // lanes -> consecutive words
    }
    __syncthreads();
    if (w == 0) {
#pragma unroll
        for (int j = 0; j < 3; ++j) {
            const float* rp = &red[j * 16 * 64 + l];
#pragma unroll
            for (int r = 0; r < 16; ++r) acc[r] += rp[r * 64];
        }
        const float bb = bias[lx];
        short* ob = out + ((size_t)img * HW + (size_t)y * W + x0) * 32 + lx;
#pragma unroll
        for (int r = 0; r < 16; ++r) {
            int row = (r & 3) + 8 * (r >> 2) + 4 * lh;
            ob[(size_t)row * 32] = f2b(acc[r] + bb);
        }
    }
}

// ---------------- launch ----------------
extern "C" void kernel_launch(void* const* d_in, const int* in_sizes, int n_in,
                              void* d_out, int out_size, void* d_ws, size_t ws_size,
                              hipStream_t stream)
{
    const float* rg  = (const float*)d_in[0];
    const float* w1  = (const float*)d_in[1];  const float* b1 = (const float*)d_in[2];
    const float* g1  = (const float*)d_in[3];  const float* be1 = (const float*)d_in[4];
    const float* m1  = (const float*)d_in[5];  const float* v1 = (const float*)d_in[6];
    const float* w2  = (const float*)d_in[7];  const float* b2 = (const float*)d_in[8];
    const float* g2  = (const float*)d_in[9];  const float* be2 = (const float*)d_in[10];
    const float* m2  = (const float*)d_in[11]; const float* v2 = (const float*)d_in[12];
    const float* w3  = (const float*)d_in[13]; const float* b3 = (const float*)d_in[14];
    const float* wo  = (const float*)d_in[15]; const float* bo = (const float*)d_in[16];
    const float* wd  = (const float*)d_in[17]; const float* bd = (const float*)d_in[18];
    const float* w4  = (const float*)d_in[19]; const float* b4 = (const float*)d_in[20];
    const float* g4  = (const float*)d_in[21]; const float* be4 = (const float*)d_in[22];
    const float* m4  = (const float*)d_in[23]; const float* v4 = (const float*)d_in[24];
    const float* w5  = (const float*)d_in[25]; const float* b5 = (const float*)d_in[26];

    short* q   = (short*)d_ws;
    float* fp  = (float*)((char*)d_ws + FPB);
    short* act = (short*)((char*)d_ws + ACTB);
    short* act1  = act + A1;
    short* act2  = act + A2;
    short* amean = act + AM;
    short* aoffs = act + AO;
    short* adf   = act + AD;
    short* a4o   = act + A4;

    prep_k<<<NPREP / 256, 256, 0, stream>>>(
        w1, b1, g1, be1, m1, v1, w2, b2, g2, be2, m2, v2, w3, b3,
        wo, bo, wd, bd, w4, b4, g4, be4, m4, v4, w5, b5, q, fp);

    // stage A (16 images)
    mconv_k<5, 1, 1, 1, 0, true,  true ><<<3200, 256, 0, stream>>>(rg,   q + Q1, fp + B1, act1);
    mconv_k<5, 2, 1, 1, 0, true,  false><<<3200, 256, 0, stream>>>(act1, q + Q2, fp + B2, act2);
    mconv_k<3, 2, 1, 4, 0, false, false><<< 800, 256, 0, stream>>>(act2, q + Q3, fp + B3, amean);

    // stage B (4 images)
    mconv_k<5, 2, 2, 1, 1, false, false><<< 800, 256, 0, stream>>>(amean, q + QO, fp + BO, aoffs);
    deform_m_k<<<3200, 256, 0, stream>>>(amean, aoffs, q + QD, fp + BD, adf);
    mconv_k<3, 2, 1, 1, 0, true,  false><<< 800, 256, 0, stream>>>(adf,  q + Q4, fp + B4, a4o);
    mconv_k<3, 2, 1, 1, 2, false, false><<< 800, 256, 0, stream>>>(a4o,  q + Q5, fp + B5, d_out);
}

// Round 17
// 263.874 us; speedup vs baseline: 4.9061x; 1.0120x over previous
//
#include <hip/hip_runtime.h>
#include <hip/hip_bf16.h>

#define DI static __device__ __forceinline__

typedef __attribute__((ext_vector_type(8)))  short short8v;   // 8 bf16 = 4 VGPR (MFMA A/B frag)
typedef __attribute__((ext_vector_type(4)))  short short4v;   // 8B
typedef __attribute__((ext_vector_type(4)))  float float4v;
typedef __attribute__((ext_vector_type(16))) float f32x16;    // MFMA C/D frag

namespace {
constexpr int H = 160, W = 160, HW = H * W;

// ---- bf16 fragment region (short offsets, base = d_ws + 0) ----
constexpr int Q1 = 0;        // conv1: 25 ksteps * 64 * 8 = 12800
constexpr int Q2 = 12800;    // conv2: 50 * 512 = 25600
constexpr int Q3 = 38400;    // conv3: 18 * 512 = 9216
constexpr int QO = 47616;    // offs : 50 * 2 * 512 = 51200
constexpr int Q4 = 98816;    // conv4: 18 * 512
constexpr int Q5 = 108032;   // conv5: 18 * 512
constexpr int QD = 117248;   // deform: 50 * 512 = 25600
constexpr int QEND = 142848;

// ---- fp32 region (byte offset, float offsets within) ----
constexpr size_t FPB = 285696;            // = QEND*2
constexpr int B1 = 0, B2 = 32, B3 = 64, BO = 96, BD = 160, B4 = 192, B5 = 224;
constexpr int NFP = 256;

// ---- activation region (byte offset, short offsets within) ----
constexpr size_t ACTB = 286720;           // FPB + NFP*4
constexpr size_t A1 = 0;                  // conv1 out: 16*HW*32 bf16
constexpr size_t A2 = 13107200;           // conv2 out
constexpr size_t AM = 26214400;           // mean: 4*HW*32
constexpr size_t AO = 29491200;           // offsets: 4*HW*64, phase-grouped (see perm)
constexpr size_t AD = 36044800;           // deform out: 4*HW*32
constexpr size_t A4 = 39321600;           // conv4 out

constexpr int NPREP = QEND + 256;         // 143104 = 559*256 exactly
} // namespace

DI float b2f(short s) {
    unsigned int u = ((unsigned int)(unsigned short)s) << 16;
    float f; __builtin_memcpy(&f, &u, 4); return f;
}
DI short f2b(float f) {
    __hip_bfloat16 h = __float2bfloat16(f);
    short s; __builtin_memcpy(&s, &h, 2); return s;
}

// offsets channel permutation: group taps by phase p = t%4 so deform wave w
// reads its 7 (dy,dx) pairs contiguously at +w*16 shorts (16B-aligned).
// oc<50: t=oc>>1, d=oc&1 -> newc = (t%4)*16 + (t/4)*2 + d.
// oc>=50 (pad): fill unused slots {14,15, 28..31, 44..47, 60..63}.
DI int offs_perm(int oc) {
    if (oc < 50) {
        int t = oc >> 1, d = oc & 1;
        return (t & 3) * 16 + (t >> 2) * 2 + d;
    }
    int i = oc - 50;
    if (i < 2)  return 14 + i;
    if (i < 6)  return 28 + (i - 2);
    if (i < 10) return 44 + (i - 6);
    return 60 + (i - 10);
}

// ---------------- prep: build per-lane MFMA B-fragments + BN fold + biases ----------------
// frag layout: [s][nt][lane][8] bf16, s = (ky*KS+kx)*ICS + h.
// B element: col oc = nt*32 + (lane&31); k = (lane>>5)*8 + j; ic = h*16 + k.
DI void fragw(int j, const float* __restrict__ w, const float* g, const float* v,
              int IC, int KS, int ICS, int NT, int OC, short* __restrict__ dst) {
    int q = j & 7;
    int l = (j >> 3) & 63;
    int rest = j >> 9;            // s*NT + nt
    int nt = rest % NT, s = rest / NT;
    int h = s % ICS, tap = s / ICS;
    int oc = nt * 32 + (l & 31);
    int ic = h * 16 + (l >> 5) * 8 + q;
    float val = 0.f;
    if (oc < OC && ic < IC) {
        val = w[((size_t)(oc * IC + ic)) * (KS * KS) + tap];
        if (g) val *= g[oc] * rsqrtf(v[oc] + 1e-5f);
    }
    dst[j] = f2b(val);
}

__global__ void prep_k(
    const float* __restrict__ w1, const float* __restrict__ b1, const float* __restrict__ g1,
    const float* __restrict__ be1, const float* __restrict__ m1, const float* __restrict__ v1,
    const float* __restrict__ w2, const float* __restrict__ b2, const float* __restrict__ g2,
    const float* __restrict__ be2, const float* __restrict__ m2, const float* __restrict__ v2,
    const float* __restrict__ w3, const float* __restrict__ b3,
    const float* __restrict__ wo, const float* __restrict__ bo,
    const float* __restrict__ wd, const float* __restrict__ bd,
    const float* __restrict__ w4, const float* __restrict__ b4, const float* __restrict__ g4,
    const float* __restrict__ be4, const float* __restrict__ m4, const float* __restrict__ v4,
    const float* __restrict__ w5, const float* __restrict__ b5,
    short* __restrict__ q, float* __restrict__ fp)
{
    int j = blockIdx.x * 256 + threadIdx.x;
    if (j >= NPREP) return;
    if (j < Q2)   { fragw(j - Q1, w1, g1, v1, 3, 5, 1, 1, 32, q + Q1); return; }
    if (j < Q3)   { fragw(j - Q2, w2, g2, v2, 32, 5, 2, 1, 32, q + Q2); return; }
    if (j < QO)   { fragw(j - Q3, w3, nullptr, nullptr, 32, 3, 2, 1, 32, q + Q3); return; }
    if (j < Q4)   { fragw(j - QO, wo, nullptr, nullptr, 32, 5, 2, 2, 50, q + QO); return; }
    if (j < Q5)   { fragw(j - Q4, w4, g4, v4, 32, 3, 2, 1, 32, q + Q4); return; }
    if (j < QD)   { fragw(j - Q5, w5, nullptr, nullptr, 32, 3, 2, 1, 3, q + Q5); return; }
    if (j < QEND) { fragw(j - QD, wd, nullptr, nullptr, 32, 5, 2, 1, 32, q + QD); return; }
    j -= QEND;
    if (j < 32) { float s = g1[j] * rsqrtf(v1[j] + 1e-5f); fp[B1 + j] = s * (b1[j] - m1[j]) + be1[j]; return; } j -= 32;
    if (j < 32) { float s = g2[j] * rsqrtf(v2[j] + 1e-5f); fp[B2 + j] = s * (b2[j] - m2[j]) + be2[j]; return; } j -= 32;
    if (j < 32) { fp[B3 + j] = b3[j]; return; } j -= 32;
    if (j < 64) { fp[BO + j] = (j < 50) ? bo[j] : 0.f; return; } j -= 64;
    if (j < 32) { fp[BD + j] = bd[j]; return; } j -= 32;
    if (j < 32) { float s = g4[j] * rsqrtf(v4[j] + 1e-5f); fp[B4 + j] = s * (b4[j] - m4[j]) + be4[j]; return; } j -= 32;
    if (j < 32) { fp[B5 + j] = (j < 3) ? b5[j] : 0.f; return; }
}

// ---------------- MFMA implicit-GEMM conv ----------------
// Block = 4 waves; wave w computes NR output rows y = yt*4*NR + w*NR + rr,
// 32 x-positions, 32*NT oc. One B-frag load feeds NR MFMAs (B reuse).
// A from LDS (NHWC tile, 72B pixel stride -> 2-way-free ds_read_b64 pairs);
// B from global precomputed frags (16B/lane, coalesced, L2-resident).
// OMODE: 0 = bf16 NHWC stride 32; 1 = bf16 NHWC stride 64 phase-grouped offsets;
//        2 = tanh fp32 NCHW oc<3.
template<int KS, int ICS, int NT, int NR, int NACC, int OMODE, bool RELU, bool IN3>
__global__ __launch_bounds__(256) void mconv_k(
    const void* __restrict__ inv, const short* __restrict__ wq,
    const float* __restrict__ bias, void* __restrict__ outv)
{
    constexpr int PAD = KS / 2, RR = 4 * NR + KS - 1, XX = 31 + KS;
    constexpr int PB = IN3 ? 40 : 72;      // pixel stride bytes (bank-spread, 8B-aligned)
    constexpr int NS = KS * KS * ICS;      // K-steps per image
    constexpr int YT = H / (4 * NR);       // y-tiles
    __shared__ __align__(16) char lds[RR * XX * PB];

    const int tid = threadIdx.x, w = tid >> 6, l = tid & 63, lx = l & 31, lh = l >> 5;
    const int b = blockIdx.x;
    const int xt = b % 5, yt = (b / 5) % YT, og = b / (5 * YT);
    const int gx0 = xt * 32 - PAD, gy0 = yt * 4 * NR - PAD;

    f32x16 acc[NR][NT];
#pragma unroll
    for (int rr = 0; rr < NR; ++rr)
#pragma unroll
        for (int nt = 0; nt < NT; ++nt)
#pragma unroll
            for (int i = 0; i < 16; ++i) acc[rr][nt][i] = 0.f;

    for (int n = 0; n < NACC; ++n) {
        if (n) __syncthreads();
        const int img = og * NACC + n;
        if (IN3) {
            // fp32 NCHW 3-ch input -> bf16, ic padded to 16
            const float* inb = (const float*)inv + (size_t)img * 3 * HW;
            for (int p = tid; p < RR * XX; p += 256) {
                int yy = p / XX, xx = p % XX, gy = gy0 + yy, gx = gx0 + xx;
                bool ok = (gy >= 0) & (gy < H) & (gx >= 0) & (gx < W);
                size_t o = (size_t)gy * W + gx;
                short4v v; v[0] = ok ? f2b(inb[o]) : (short)0;
                v[1] = ok ? f2b(inb[HW + o]) : (short)0;
                v[2] = ok ? f2b(inb[2 * HW + o]) : (short)0; v[3] = 0;
                short4v z; z[0] = z[1] = z[2] = z[3] = 0;
                char* dst = lds + p * PB;
                *(short4v*)dst = v;
                *(short4v*)(dst + 8) = z;
                *(short4v*)(dst + 16) = z;
                *(short4v*)(dst + 24) = z;
            }
        } else {
            // bf16 NHWC 32-ch input, staged in 8B chunks (72B stride is 8B-aligned)
            const short* inb = (const short*)inv + (size_t)img * HW * 32;
            for (int c = tid; c < RR * XX * 8; c += 256) {
                int p = c >> 3, cc = c & 7;
                int yy = p / XX, xx = p % XX, gy = gy0 + yy, gx = gx0 + xx;
                short4v v;
                if ((gy >= 0) & (gy < H) & (gx >= 0) & (gx < W))
                    v = *(const short4v*)(inb + ((size_t)gy * W + gx) * 32 + cc * 4);
                else { v[0] = v[1] = v[2] = v[3] = 0; }
                *(short4v*)(lds + p * PB + cc * 8) = v;
            }
        }
        __syncthreads();

#pragma unroll
        for (int s = 0; s < NS; ++s) {
            const int tap = s / ICS, hh = s % ICS;
            const int ky = tap / KS, kx = tap % KS;
            short8v bf[NT];
#pragma unroll
            for (int nt = 0; nt < NT; ++nt)
                bf[nt] = *(const short8v*)(wq + ((size_t)(s * NT + nt) * 64 + l) * 8);
#pragma unroll
            for (int rr = 0; rr < NR; ++rr) {
                const char* ap = lds + ((w * NR + rr + ky) * XX + lx + kx) * PB + hh * 32 + lh * 16;
                union { short4v h[2]; short8v v; } u;
                u.h[0] = *(const short4v*)ap;
                u.h[1] = *(const short4v*)(ap + 8);
#pragma unroll
                for (int nt = 0; nt < NT; ++nt)
                    acc[rr][nt] = __builtin_amdgcn_mfma_f32_32x32x16_bf16(u.v, bf[nt], acc[rr][nt], 0, 0, 0);
            }
        }
    }

    constexpr float MS = (NACC == 4) ? 0.25f : 1.f;
#pragma unroll
    for (int rr = 0; rr < NR; ++rr) {
        const int y = yt * 4 * NR + w * NR + rr;
        if (OMODE == 0) {
            const float bb = bias[lx];
            short* ob = (short*)outv + ((size_t)og * HW + (size_t)y * W + xt * 32) * 32 + lx;
#pragma unroll
            for (int r = 0; r < 16; ++r) {
                int row = (r & 3) + 8 * (r >> 2) + 4 * lh;   // x offset within tile
                float vv = acc[rr][0][r] * MS + bb;
                if (RELU) vv = fmaxf(vv, 0.f);
                ob[(size_t)row * 32] = f2b(vv);
            }
        } else if (OMODE == 1) {
            short* ob = (short*)outv + ((size_t)og * HW + (size_t)y * W + xt * 32) * 64;
#pragma unroll
            for (int nt = 0; nt < NT; ++nt) {
                const int oc = nt * 32 + lx;
                const float bb = bias[oc];
                const int nc = offs_perm(oc);          // phase-grouped channel
#pragma unroll
                for (int r = 0; r < 16; ++r) {
                    int row = (r & 3) + 8 * (r >> 2) + 4 * lh;
                    ob[(size_t)row * 64 + nc] = f2b(acc[rr][nt][r] + bb);
                }
            }
        } else {
            const int oc = lx;
            const float bb = bias[oc];
            float* ob = (float*)outv;
#pragma unroll
            for (int r = 0; r < 16; ++r) {
                int row = (r & 3) + 8 * (r >> 2) + 4 * lh;
                float vv = tanhf(acc[rr][0][r] + bb);
                if (oc < 3)
                    ob[(((size_t)og * 3 + oc) * H + y) * W + xt * 32 + row] = vv;
            }
        }
    }
}

// ---------------- deformable conv via MFMA, tap-split across 4 waves ----------------
// Block = 4 waves, ONE 32-pixel strip. Wave w handles taps t = 4*tt+w (7/6/6/6),
// compile-time unrolled for ILP. Offsets are phase-grouped: wave w's 7 (dy,dx)
// pairs are contiguous at +w*16 shorts (two aligned 16B loads).
// Partial f32x16 reduce via lane-major LDS [3][16][64] (conflict-free).
__global__ __launch_bounds__(256) void deform_m_k(
    const short* __restrict__ xn,   // mean NHWC bf16 [4][HW][32]
    const short* __restrict__ offs, // phase-grouped bf16 [4][HW][64]
    const short* __restrict__ wq,   // deform B-frags [50][64][8]
    const float* __restrict__ bias,
    short* __restrict__ out)        // NHWC bf16 [4][HW][32]
{
    __shared__ float red[3 * 16 * 64];   // 12 KB, lane-major

    const int tid = threadIdx.x, w = tid >> 6, l = tid & 63, lx = l & 31, lh = l >> 5;
    const int S = blockIdx.x;          // strip id, 3200 total
    const int x0 = (S % 5) * 32;
    const int y  = (S / 5) % H;
    const int img = S / 800;
    const int px = x0 + lx;

    const short* xb = xn + (size_t)img * HW * 32;
    const short* op2 = offs + ((size_t)img * HW + (size_t)y * W + px) * 64 + w * 16;

    union { short8v v2[2]; short s[16]; } pp;
    pp.v2[0] = *(const short8v*)(op2);
    pp.v2[1] = *(const short8v*)(op2 + 8);

    f32x16 acc;
#pragma unroll
    for (int i = 0; i < 16; ++i) acc[i] = 0.f;

#pragma unroll
    for (int tt = 0; tt < 7; ++tt) {
        const int t = 4 * tt + w;
        if (t < 25) {
            const int ky = t / 5, kx = t % 5;
            float dy = b2f(pp.s[2 * tt]);
            float dx = b2f(pp.s[2 * tt + 1]);
            float py  = (float)(y - 2 + ky) + dy;
            float pxf = (float)(px - 2 + kx) + dx;
            float fy = floorf(py), fx = floorf(pxf);
            float wy = py - fy, wx = pxf - fx;
            int iy = (int)fy, ix = (int)fx;

            float wgt[4]; const short* cp[4]; bool ok[4];
#pragma unroll
            for (int c = 0; c < 4; ++c) {
                int yy = iy + (c >> 1), xx = ix + (c & 1);
                ok[c] = (yy >= 0) & (yy < H) & (xx >= 0) & (xx < W);
                wgt[c] = ((c >> 1) ? wy : 1.f - wy) * ((c & 1) ? wx : 1.f - wx);
                cp[c] = xb + ((size_t)yy * W + xx) * 32;
            }

#pragma unroll
            for (int h = 0; h < 2; ++h) {
                const int ic0 = h * 16 + lh * 8;
                float va[8];
#pragma unroll
                for (int j = 0; j < 8; ++j) va[j] = 0.f;
#pragma unroll
                for (int c = 0; c < 4; ++c) {
                    if (ok[c]) {
                        short8v g = *(const short8v*)(cp[c] + ic0);
#pragma unroll
                        for (int j = 0; j < 8; ++j) va[j] = fmaf(wgt[c], b2f(g[j]), va[j]);
                    }
                }
                short8v u;
#pragma unroll
                for (int j = 0; j < 8; ++j) u[j] = f2b(va[j]);
                short8v bf = *(const short8v*)(wq + ((size_t)(t * 2 + h) * 64 + l) * 8);
                acc = __builtin_amdgcn_mfma_f32_32x32x16_bf16(u, bf, acc, 0, 0, 0);
            }
        }
    }

    if (w) {
        float* rp = &red[(w - 1) * 16 * 64 + l];
#pragma unroll
        for (int r = 0; r < 16; ++r) rp[r * 64] = acc[r];   // lanes -> consecutive words
    }
    __syncthreads();
    if (w == 0) {
#pragma unroll
        for (int j = 0; j < 3; ++j) {
            const float* rp = &red[j * 16 * 64 + l];
#pragma unroll
            for (int r = 0; r < 16; ++r) acc[r] += rp[r * 64];
        }
        const float bb = bias[lx];
        short* ob = out + ((size_t)img * HW + (size_t)y * W + x0) * 32 + lx;
#pragma unroll
        for (int r = 0; r < 16; ++r) {
            int row = (r & 3) + 8 * (r >> 2) + 4 * lh;
            ob[(size_t)row * 32] = f2b(acc[r] + bb);
        }
    }
}

// ---------------- launch ----------------
extern "C" void kernel_launch(void* const* d_in, const int* in_sizes, int n_in,
                              void* d_out, int out_size, void* d_ws, size_t ws_size,
                              hipStream_t stream)
{
    const float* rg  = (const float*)d_in[0];
    const float* w1  = (const float*)d_in[1];  const float* b1 = (const float*)d_in[2];
    const float* g1  = (const float*)d_in[3];  const float* be1 = (const float*)d_in[4];
    const float* m1  = (const float*)d_in[5];  const float* v1 = (const float*)d_in[6];
    const float* w2  = (const float*)d_in[7];  const float* b2 = (const float*)d_in[8];
    const float* g2  = (const float*)d_in[9];  const float* be2 = (const float*)d_in[10];
    const float* m2  = (const float*)d_in[11]; const float* v2 = (const float*)d_in[12];
    const float* w3  = (const float*)d_in[13]; const float* b3 = (const float*)d_in[14];
    const float* wo  = (const float*)d_in[15]; const float* bo = (const float*)d_in[16];
    const float* wd  = (const float*)d_in[17]; const float* bd = (const float*)d_in[18];
    const float* w4  = (const float*)d_in[19]; const float* b4 = (const float*)d_in[20];
    const float* g4  = (const float*)d_in[21]; const float* be4 = (const float*)d_in[22];
    const float* m4  = (const float*)d_in[23]; const float* v4 = (const float*)d_in[24];
    const float* w5  = (const float*)d_in[25]; const float* b5 = (const float*)d_in[26];

    short* q   = (short*)d_ws;
    float* fp  = (float*)((char*)d_ws + FPB);
    short* act = (short*)((char*)d_ws + ACTB);
    short* act1  = act + A1;
    short* act2  = act + A2;
    short* amean = act + AM;
    short* aoffs = act + AO;
    short* adf   = act + AD;
    short* a4o   = act + A4;

    prep_k<<<NPREP / 256, 256, 0, stream>>>(
        w1, b1, g1, be1, m1, v1, w2, b2, g2, be2, m2, v2, w3, b3,
        wo, bo, wd, bd, w4, b4, g4, be4, m4, v4, w5, b5, q, fp);

    // stage A (16 images): NR=2 -> 8 rows/block, 1600 blocks, B-frag reuse x2
    mconv_k<5, 1, 1, 2, 1, 0, true,  true ><<<1600, 256, 0, stream>>>(rg,   q + Q1, fp + B1, act1);
    mconv_k<5, 2, 1, 2, 1, 0, true,  false><<<1600, 256, 0, stream>>>(act1, q + Q2, fp + B2, act2);
    mconv_k<3, 2, 1, 1, 4, 0, false, false><<< 800, 256, 0, stream>>>(act2, q + Q3, fp + B3, amean);

    // stage B (4 images)
    mconv_k<5, 2, 2, 1, 1, 1, false, false><<< 800, 256, 0, stream>>>(amean, q + QO, fp + BO, aoffs);
    deform_m_k<<<3200, 256, 0, stream>>>(amean, aoffs, q + QD, fp + BD, adf);
    mconv_k<3, 2, 1, 1, 1, 0, true,  false><<< 800, 256, 0, stream>>>(adf,  q + Q4, fp + B4, a4o);
    mconv_k<3, 2, 1, 1, 1, 2, false, false><<< 800, 256, 0, stream>>>(a4o,  q + Q5, fp + B5, d_out);
}